// Round 1
// baseline (4016.024 us; speedup 1.0000x reference)
//
#include <hip/hip_runtime.h>
#include <hip/hip_bf16.h>
#include <math.h>

#define B_    4
#define LQ_   2048
#define LK_   2048
#define D_    1024
#define H_    16
#define DK_   64
#define DV_   64
#define TEMP_ 8.0f
#define LN_EPS_ 1e-5f

// ---------------------------------------------------------------------------
// Kernel 1: fused QKV projection.  C = X @ W + b, written to [B,H,L,64].
// M=8192, N=1024, K=1024.  64x64 tile, TK=16, 256 threads, 4x4 per thread.
// grid.z = 0/1/2 selects q/k/v.
// ---------------------------------------------------------------------------
__global__ __launch_bounds__(256) void proj_kernel(
    const float* __restrict__ Xq, const float* __restrict__ Xk, const float* __restrict__ Xv,
    const float* __restrict__ Wq, const float* __restrict__ bq,
    const float* __restrict__ Wk, const float* __restrict__ bk,
    const float* __restrict__ Wv, const float* __restrict__ bv,
    float* __restrict__ qh, float* __restrict__ kh, float* __restrict__ vh)
{
    const int which = blockIdx.z;
    const float* X    = which == 0 ? Xq : (which == 1 ? Xk : Xv);
    const float* W    = which == 0 ? Wq : (which == 1 ? Wk : Wv);
    const float* bias = which == 0 ? bq : (which == 1 ? bk : bv);
    float* out        = which == 0 ? qh : (which == 1 ? kh : vh);

    __shared__ float As[16][68];   // [k][m], padded
    __shared__ float Bs[16][64];   // [k][n]

    const int t  = threadIdx.x;
    const int tx = t & 15, ty = t >> 4;
    const int m0 = blockIdx.y * 64;
    const int n0 = blockIdx.x * 64;

    float acc[4][4] = {};
    for (int k0 = 0; k0 < 1024; k0 += 16) {
        {   // A tile: 64 rows x 16 k.  thread t: row t>>2, k (t&3)*4, float4
            int m = t >> 2, kq = (t & 3) * 4;
            const float4 a = *reinterpret_cast<const float4*>(&X[(size_t)(m0 + m) * 1024 + k0 + kq]);
            As[kq + 0][m] = a.x; As[kq + 1][m] = a.y; As[kq + 2][m] = a.z; As[kq + 3][m] = a.w;
            // B tile: 16 rows x 64 n.  thread t: row t>>4, n (t&15)*4, float4
            int kk = t >> 4, n = (t & 15) * 4;
            *reinterpret_cast<float4*>(&Bs[kk][n]) =
                *reinterpret_cast<const float4*>(&W[(size_t)(k0 + kk) * 1024 + n0 + n]);
        }
        __syncthreads();
        #pragma unroll
        for (int kk = 0; kk < 16; ++kk) {
            const float4 a4 = *reinterpret_cast<const float4*>(&As[kk][ty * 4]);
            const float4 b4 = *reinterpret_cast<const float4*>(&Bs[kk][tx * 4]);
            const float a[4] = {a4.x, a4.y, a4.z, a4.w};
            const float b[4] = {b4.x, b4.y, b4.z, b4.w};
            #pragma unroll
            for (int i = 0; i < 4; ++i)
                #pragma unroll
                for (int j = 0; j < 4; ++j)
                    acc[i][j] += a[i] * b[j];
        }
        __syncthreads();
    }
    #pragma unroll
    for (int i = 0; i < 4; ++i) {
        int mg = m0 + ty * 4 + i;
        int bb = mg >> 11;        // / 2048
        int l  = mg & 2047;
        #pragma unroll
        for (int j = 0; j < 4; ++j) {
            int ng = n0 + tx * 4 + j;
            int h = ng >> 6, dh = ng & 63;
            out[(((size_t)(bb * H_ + h)) * LQ_ + l) * 64 + dh] = acc[i][j] + bias[ng];
        }
    }
}

// ---------------------------------------------------------------------------
// Kernel 2: flash attention (f32).  One block per (b, h, 32 q-rows).
// Online softmax over K-tiles of 32; writes ctx [B,LQ,H*64] and final
// per-row stats (max m, sumexp s) for the avg kernel.
// ---------------------------------------------------------------------------
__global__ __launch_bounds__(256) void flash_kernel(
    const float* __restrict__ qh, const float* __restrict__ kh, const float* __restrict__ vh,
    const int* __restrict__ mask,
    float* __restrict__ ctx, float* __restrict__ mOut, float* __restrict__ sOut)
{
    const int q0 = blockIdx.x * 32;
    const int h  = blockIdx.y;
    const int b  = blockIdx.z;

    __shared__ float Qs[32][68];
    __shared__ float Ks[32][68];
    __shared__ float Vs[32][68];
    __shared__ float Ps[32][33];

    const int t = threadIdx.x;
    const int r = t >> 3;   // q-row within tile, 0..31
    const int g = t & 7;    // lane group 0..7

    const float* Qb = qh + (((size_t)(b * H_ + h)) * LQ_ + q0) * 64;
    const float* Kb = kh + ((size_t)(b * H_ + h)) * LK_ * 64;
    const float* Vb = vh + ((size_t)(b * H_ + h)) * LK_ * 64;
    const int*   mb = mask + b * LK_;

    {   // load Q tile (32x64), 8 floats per thread
        int row = t >> 3, col = (t & 7) * 8;
        *reinterpret_cast<float4*>(&Qs[row][col])     = *reinterpret_cast<const float4*>(&Qb[row * 64 + col]);
        *reinterpret_cast<float4*>(&Qs[row][col + 4]) = *reinterpret_cast<const float4*>(&Qb[row * 64 + col + 4]);
    }

    float m_run = -INFINITY, s_run = 0.f;
    float cacc[8] = {};
    const int dv0 = g * 8;

    for (int k0 = 0; k0 < LK_; k0 += 32) {
        __syncthreads();   // protect Ks/Vs/Ps from previous iteration readers
        {
            int row = t >> 3, col = (t & 7) * 8;
            *reinterpret_cast<float4*>(&Ks[row][col])     = *reinterpret_cast<const float4*>(&Kb[(size_t)(k0 + row) * 64 + col]);
            *reinterpret_cast<float4*>(&Ks[row][col + 4]) = *reinterpret_cast<const float4*>(&Kb[(size_t)(k0 + row) * 64 + col + 4]);
            *reinterpret_cast<float4*>(&Vs[row][col])     = *reinterpret_cast<const float4*>(&Vb[(size_t)(k0 + row) * 64 + col]);
            *reinterpret_cast<float4*>(&Vs[row][col + 4]) = *reinterpret_cast<const float4*>(&Vb[(size_t)(k0 + row) * 64 + col + 4]);
        }
        __syncthreads();

        // QK^T: thread computes 4 logits, cols c = g*4+j
        float lg[4];
        bool  msk[4];
        #pragma unroll
        for (int j = 0; j < 4; ++j) {
            const int c = g * 4 + j;
            msk[j] = (mb[k0 + c] != 0);
            float acc = 0.f;
            #pragma unroll
            for (int d = 0; d < 64; d += 4) {
                const float4 qv = *reinterpret_cast<const float4*>(&Qs[r][d]);
                const float4 kv = *reinterpret_cast<const float4*>(&Ks[c][d]);
                acc += qv.x * kv.x + qv.y * kv.y + qv.z * kv.z + qv.w * kv.w;
            }
            lg[j] = acc * (1.0f / TEMP_);
        }
        float lmax = -INFINITY;
        #pragma unroll
        for (int j = 0; j < 4; ++j) if (!msk[j]) lmax = fmaxf(lmax, lg[j]);
        #pragma unroll
        for (int w = 1; w < 8; w <<= 1) lmax = fmaxf(lmax, __shfl_xor(lmax, w));

        const float m_new = fmaxf(m_run, lmax);
        float p[4]; float lsum = 0.f;
        #pragma unroll
        for (int j = 0; j < 4; ++j) {
            p[j] = (msk[j] || m_new == -INFINITY) ? 0.f : expf(lg[j] - m_new);
            lsum += p[j];
        }
        #pragma unroll
        for (int w = 1; w < 8; w <<= 1) lsum += __shfl_xor(lsum, w);

        const float alpha = (m_run == -INFINITY) ? 0.f : expf(m_run - m_new);
        s_run = s_run * alpha + lsum;
        m_run = m_new;
        #pragma unroll
        for (int j = 0; j < 4; ++j) Ps[r][g * 4 + j] = p[j];
        #pragma unroll
        for (int i = 0; i < 8; ++i) cacc[i] *= alpha;
        __syncthreads();

        // PV: ctx[r][dv0..dv0+7] += sum_kk P[r][kk] * V[kk][dv]
        #pragma unroll 8
        for (int kk = 0; kk < 32; ++kk) {
            const float pv = Ps[r][kk];
            const float4 v0 = *reinterpret_cast<const float4*>(&Vs[kk][dv0]);
            const float4 v1 = *reinterpret_cast<const float4*>(&Vs[kk][dv0 + 4]);
            cacc[0] += pv * v0.x; cacc[1] += pv * v0.y; cacc[2] += pv * v0.z; cacc[3] += pv * v0.w;
            cacc[4] += pv * v1.x; cacc[5] += pv * v1.y; cacc[6] += pv * v1.z; cacc[7] += pv * v1.w;
        }
    }

    const float rs = (s_run > 0.f) ? 1.0f / s_run : 0.f;
    float* co = ctx + ((size_t)b * LQ_ + q0 + r) * (H_ * DV_) + h * 64 + dv0;
    #pragma unroll
    for (int i = 0; i < 8; ++i) co[i] = cacc[i] * rs;
    if (g == 0) {
        mOut[((size_t)(b * H_ + h)) * LQ_ + q0 + r] = m_run;
        sOut[((size_t)(b * H_ + h)) * LQ_ + q0 + r] = s_run;
    }
}

// ---------------------------------------------------------------------------
// Kernel 3: attn_avg.  One block per (b, q-tile32, k-tile32); loops 16 heads,
// recomputes logits, p = exp(l - m)/s, accumulates mean over heads.
// ---------------------------------------------------------------------------
__global__ __launch_bounds__(256) void avg_kernel(
    const float* __restrict__ qh, const float* __restrict__ kh,
    const int* __restrict__ mask,
    const float* __restrict__ mIn, const float* __restrict__ sIn,
    float* __restrict__ attn_avg)
{
    const int k0 = blockIdx.x * 32;
    const int q0 = blockIdx.y * 32;
    const int b  = blockIdx.z;

    __shared__ float Qs[32][68];
    __shared__ float Ks[32][68];

    const int t = threadIdx.x;
    const int r = t >> 3, g = t & 7;

    const int* mb = mask + b * LK_;
    bool msk[4];
    #pragma unroll
    for (int j = 0; j < 4; ++j) msk[j] = (mb[k0 + g * 4 + j] != 0);

    float acc[4] = {};
    for (int h = 0; h < H_; ++h) {
        __syncthreads();
        {
            int row = t >> 3, col = (t & 7) * 8;
            const float* Qb = qh + (((size_t)(b * H_ + h)) * LQ_ + q0) * 64;
            const float* Kb = kh + (((size_t)(b * H_ + h)) * LK_ + k0) * 64;
            *reinterpret_cast<float4*>(&Qs[row][col])     = *reinterpret_cast<const float4*>(&Qb[row * 64 + col]);
            *reinterpret_cast<float4*>(&Qs[row][col + 4]) = *reinterpret_cast<const float4*>(&Qb[row * 64 + col + 4]);
            *reinterpret_cast<float4*>(&Ks[row][col])     = *reinterpret_cast<const float4*>(&Kb[row * 64 + col]);
            *reinterpret_cast<float4*>(&Ks[row][col + 4]) = *reinterpret_cast<const float4*>(&Kb[row * 64 + col + 4]);
        }
        __syncthreads();

        const float mrow = mIn[((size_t)(b * H_ + h)) * LQ_ + q0 + r];
        const float srow = sIn[((size_t)(b * H_ + h)) * LQ_ + q0 + r];
        const float rsd  = (srow > 0.f) ? 1.0f / srow : 0.f;

        float l[4] = {};
        #pragma unroll 4
        for (int d = 0; d < 64; d += 4) {
            const float4 qv = *reinterpret_cast<const float4*>(&Qs[r][d]);
            #pragma unroll
            for (int j = 0; j < 4; ++j) {
                const float4 kv = *reinterpret_cast<const float4*>(&Ks[g * 4 + j][d]);
                l[j] += qv.x * kv.x + qv.y * kv.y + qv.z * kv.z + qv.w * kv.w;
            }
        }
        #pragma unroll
        for (int j = 0; j < 4; ++j) {
            if (!msk[j] && mrow != -INFINITY)
                acc[j] += expf(l[j] * (1.0f / TEMP_) - mrow) * rsd;
        }
    }
    float4 o;
    o.x = acc[0] * (1.0f / H_); o.y = acc[1] * (1.0f / H_);
    o.z = acc[2] * (1.0f / H_); o.w = acc[3] * (1.0f / H_);
    *reinterpret_cast<float4*>(&attn_avg[((size_t)b * LQ_ + q0 + r) * LK_ + k0 + g * 4]) = o;
}

// ---------------------------------------------------------------------------
// Kernel 4: out-projection + bias + residual.  pre_ln = ctx @ Wo + bo + q
// ---------------------------------------------------------------------------
__global__ __launch_bounds__(256) void outproj_kernel(
    const float* __restrict__ ctxIn, const float* __restrict__ Wo, const float* __restrict__ bo,
    const float* __restrict__ resid, float* __restrict__ preln)
{
    __shared__ float As[16][68];
    __shared__ float Bs[16][64];

    const int t  = threadIdx.x;
    const int tx = t & 15, ty = t >> 4;
    const int m0 = blockIdx.y * 64;
    const int n0 = blockIdx.x * 64;

    float acc[4][4] = {};
    for (int k0 = 0; k0 < 1024; k0 += 16) {
        {
            int m = t >> 2, kq = (t & 3) * 4;
            const float4 a = *reinterpret_cast<const float4*>(&ctxIn[(size_t)(m0 + m) * 1024 + k0 + kq]);
            As[kq + 0][m] = a.x; As[kq + 1][m] = a.y; As[kq + 2][m] = a.z; As[kq + 3][m] = a.w;
            int kk = t >> 4, n = (t & 15) * 4;
            *reinterpret_cast<float4*>(&Bs[kk][n]) =
                *reinterpret_cast<const float4*>(&Wo[(size_t)(k0 + kk) * 1024 + n0 + n]);
        }
        __syncthreads();
        #pragma unroll
        for (int kk = 0; kk < 16; ++kk) {
            const float4 a4 = *reinterpret_cast<const float4*>(&As[kk][ty * 4]);
            const float4 b4 = *reinterpret_cast<const float4*>(&Bs[kk][tx * 4]);
            const float a[4] = {a4.x, a4.y, a4.z, a4.w};
            const float b[4] = {b4.x, b4.y, b4.z, b4.w};
            #pragma unroll
            for (int i = 0; i < 4; ++i)
                #pragma unroll
                for (int j = 0; j < 4; ++j)
                    acc[i][j] += a[i] * b[j];
        }
        __syncthreads();
    }
    #pragma unroll
    for (int i = 0; i < 4; ++i) {
        const size_t mg = m0 + ty * 4 + i;
        #pragma unroll
        for (int j = 0; j < 4; ++j) {
            const int ng = n0 + tx * 4 + j;
            preln[mg * 1024 + ng] = acc[i][j] + bo[ng] + resid[mg * 1024 + ng];
        }
    }
}

// ---------------------------------------------------------------------------
// Kernel 5: LayerNorm over D=1024.  One block (256 threads) per row.
// ---------------------------------------------------------------------------
__global__ __launch_bounds__(256) void ln_kernel(
    const float* __restrict__ xin, const float* __restrict__ gam,
    const float* __restrict__ bet, float* __restrict__ out)
{
    const size_t row = blockIdx.x;
    const int t = threadIdx.x;
    const float4 v = *reinterpret_cast<const float4*>(&xin[row * 1024 + t * 4]);

    float s  = v.x + v.y + v.z + v.w;
    float ss = v.x * v.x + v.y * v.y + v.z * v.z + v.w * v.w;
    #pragma unroll
    for (int w = 1; w < 64; w <<= 1) { s += __shfl_xor(s, w); ss += __shfl_xor(ss, w); }

    __shared__ float rs_[4], rss_[4];
    if ((t & 63) == 0) { rs_[t >> 6] = s; rss_[t >> 6] = ss; }
    __syncthreads();
    s  = rs_[0] + rs_[1] + rs_[2] + rs_[3];
    ss = rss_[0] + rss_[1] + rss_[2] + rss_[3];

    const float mean = s * (1.0f / 1024.0f);
    const float var  = ss * (1.0f / 1024.0f) - mean * mean;
    const float rstd = rsqrtf(var + LN_EPS_);

    const float4 g4 = *reinterpret_cast<const float4*>(&gam[t * 4]);
    const float4 b4 = *reinterpret_cast<const float4*>(&bet[t * 4]);
    float4 o;
    o.x = (v.x - mean) * rstd * g4.x + b4.x;
    o.y = (v.y - mean) * rstd * g4.y + b4.y;
    o.z = (v.z - mean) * rstd * g4.z + b4.z;
    o.w = (v.w - mean) * rstd * g4.w + b4.w;
    *reinterpret_cast<float4*>(&out[row * 1024 + t * 4]) = o;
}

// ---------------------------------------------------------------------------
extern "C" void kernel_launch(void* const* d_in, const int* in_sizes, int n_in,
                              void* d_out, int out_size, void* d_ws, size_t ws_size,
                              hipStream_t stream)
{
    const float* q    = (const float*)d_in[0];
    const float* k    = (const float*)d_in[1];
    const float* v    = (const float*)d_in[2];
    const int*   mask = (const int*)d_in[3];
    const float* Wq   = (const float*)d_in[4];
    const float* bq   = (const float*)d_in[5];
    const float* Wk   = (const float*)d_in[6];
    const float* bk   = (const float*)d_in[7];
    const float* Wv   = (const float*)d_in[8];
    const float* bv   = (const float*)d_in[9];
    const float* Wo   = (const float*)d_in[10];
    const float* bo   = (const float*)d_in[11];
    const float* lng  = (const float*)d_in[12];
    const float* lnb  = (const float*)d_in[13];

    float* out      = (float*)d_out;                    // [B,LQ,D]
    float* attn_avg = out + (size_t)B_ * LQ_ * D_;      // [B,LQ,LK]

    float* ws  = (float*)d_ws;
    float* qh  = ws;                                    // [B,H,LQ,64]
    float* kh  = qh  + (size_t)B_ * H_ * LQ_ * DK_;
    float* vh  = kh  + (size_t)B_ * H_ * LK_ * DK_;
    float* ctx = vh  + (size_t)B_ * H_ * LK_ * DV_;     // [B,LQ,H*64]
    float* mSt = ctx + (size_t)B_ * LQ_ * H_ * DV_;     // [B,H,LQ]
    float* sSt = mSt + (size_t)B_ * H_ * LQ_;           // [B,H,LQ]
    float* preln = qh;  // reuse qh region after avg_kernel has consumed it

    dim3 gProj(1024 / 64, 8192 / 64, 3);
    proj_kernel<<<gProj, 256, 0, stream>>>(q, k, v, Wq, bq, Wk, bk, Wv, bv, qh, kh, vh);

    dim3 gFlash(LQ_ / 32, H_, B_);
    flash_kernel<<<gFlash, 256, 0, stream>>>(qh, kh, vh, mask, ctx, mSt, sSt);

    dim3 gAvg(LK_ / 32, LQ_ / 32, B_);
    avg_kernel<<<gAvg, 256, 0, stream>>>(qh, kh, mask, mSt, sSt, attn_avg);

    dim3 gOut(1024 / 64, 8192 / 64);
    outproj_kernel<<<gOut, 256, 0, stream>>>(ctx, Wo, bo, q, preln);

    ln_kernel<<<8192, 256, 0, stream>>>(preln, lng, lnb, out);
}

// Round 2
// 409.788 us; speedup vs baseline: 9.8002x; 9.8002x over previous
//
#include <hip/hip_runtime.h>
#include <hip/hip_bf16.h>
#include <math.h>

#define B_    4
#define LQ_   2048
#define LK_   2048
#define D_    1024
#define H_    16
#define LN_EPS_ 1e-5f
#define NEGINF (-__builtin_inff())

typedef __attribute__((ext_vector_type(8))) short bf16x8;
typedef __attribute__((ext_vector_type(4))) short bf16x4;
typedef __attribute__((ext_vector_type(4))) float f32x4;

#define MFMA(a, b, c) __builtin_amdgcn_mfma_f32_16x16x32_bf16(a, b, c, 0, 0, 0)

__device__ __forceinline__ short f2bf(float f) {
    union { __hip_bfloat16 h; short s; } u;
    u.h = __float2bfloat16(f);
    return u.s;
}

__device__ __forceinline__ void gld16(const short* g, short* l) {
    __builtin_amdgcn_global_load_lds(
        (const __attribute__((address_space(1))) void*)g,
        (__attribute__((address_space(3))) void*)l, 16, 0, 0);
}

// ---------------------------------------------------------------------------
// cast_x: f32 -> bf16 straight copy of q/k/v; also builds additive mask.
// ---------------------------------------------------------------------------
__global__ __launch_bounds__(256) void cast_x_kernel(
    const float* __restrict__ q, const float* __restrict__ k, const float* __restrict__ v,
    const int* __restrict__ mask,
    short* __restrict__ Xq, short* __restrict__ Xk, short* __restrict__ Xv,
    float* __restrict__ maskf)
{
    const int which = blockIdx.y;
    const float* src = which == 0 ? q : (which == 1 ? k : v);
    short* dst       = which == 0 ? Xq : (which == 1 ? Xk : Xv);
    const int t = threadIdx.x;
    const size_t i = ((size_t)blockIdx.x * 256 + t) * 8;
    const float4 a = *reinterpret_cast<const float4*>(src + i);
    const float4 c = *reinterpret_cast<const float4*>(src + i + 4);
    bf16x8 o;
    o[0] = f2bf(a.x); o[1] = f2bf(a.y); o[2] = f2bf(a.z); o[3] = f2bf(a.w);
    o[4] = f2bf(c.x); o[5] = f2bf(c.y); o[6] = f2bf(c.z); o[7] = f2bf(c.w);
    *reinterpret_cast<bf16x8*>(dst + i) = o;
    if (which == 0) {
        const int gid = blockIdx.x * 256 + t;
        if (gid < B_ * LK_) maskf[gid] = (mask[gid] != 0) ? NEGINF : 0.0f;
    }
}

// ---------------------------------------------------------------------------
// cast_wt: W[k][n] f32 -> Wt[n][k] bf16 (transposed), 64x64 LDS tiles.
// ---------------------------------------------------------------------------
__global__ __launch_bounds__(256) void cast_wt_kernel(
    const float* __restrict__ Wq, const float* __restrict__ Wk,
    const float* __restrict__ Wv, const float* __restrict__ Wo,
    short* __restrict__ Wtq, short* __restrict__ Wtk,
    short* __restrict__ Wtv, short* __restrict__ Wto)
{
    const int which = blockIdx.z;
    const float* W = which == 0 ? Wq : (which == 1 ? Wk : (which == 2 ? Wv : Wo));
    short* Wt      = which == 0 ? Wtq : (which == 1 ? Wtk : (which == 2 ? Wtv : Wto));

    __shared__ float T[64][65];
    const int t = threadIdx.x;
    const int k0 = blockIdx.x * 64, n0 = blockIdx.y * 64;
    {
        const int row = t >> 2, cq = (t & 3) * 16;
        #pragma unroll
        for (int i = 0; i < 4; ++i) {
            const float4 v4 = *reinterpret_cast<const float4*>(&W[(size_t)(k0 + row) * 1024 + n0 + cq + i * 4]);
            T[row][cq + i * 4 + 0] = v4.x; T[row][cq + i * 4 + 1] = v4.y;
            T[row][cq + i * 4 + 2] = v4.z; T[row][cq + i * 4 + 3] = v4.w;
        }
    }
    __syncthreads();
    const int nl = t >> 2, kq = (t & 3) * 16;
    bf16x8 o0, o1;
    #pragma unroll
    for (int j = 0; j < 8; ++j) {
        o0[j] = f2bf(T[kq + j][nl]);
        o1[j] = f2bf(T[kq + 8 + j][nl]);
    }
    *reinterpret_cast<bf16x8*>(&Wt[(size_t)(n0 + nl) * 1024 + k0 + kq]) = o0;
    *reinterpret_cast<bf16x8*>(&Wt[(size_t)(n0 + nl) * 1024 + k0 + kq + 8]) = o1;
}

// ---------------------------------------------------------------------------
// proj: C = X(bf16)[M=8192,K=1024] @ Wt^T + bias.  128x128 tile, BK=32,
// 4 waves (2x2), 4x4 16x16 frags per wave.  global_load_lds w/ pre-swizzled
// source (chunk ^ ((row>>1)&3)).  which: 0->qh, 1->kh, 2->vT (transposed).
// ---------------------------------------------------------------------------
__global__ __launch_bounds__(256) void proj_kernel(
    const short* __restrict__ Xq, const short* __restrict__ Xk, const short* __restrict__ Xv,
    const short* __restrict__ Wtq, const short* __restrict__ Wtk, const short* __restrict__ Wtv,
    const float* __restrict__ bq, const float* __restrict__ bk, const float* __restrict__ bv,
    short* __restrict__ qh, short* __restrict__ kh, short* __restrict__ vT)
{
    const int which = blockIdx.z;
    const short* A  = which == 0 ? Xq : (which == 1 ? Xk : Xv);
    const short* Bt = which == 0 ? Wtq : (which == 1 ? Wtk : Wtv);
    const float* bias = which == 0 ? bq : (which == 1 ? bk : bv);

    __shared__ short Al[4096];   // [128 rows m][32 k], swizzled chunks
    __shared__ short Bl[4096];   // [128 rows n][32 k], swizzled chunks

    const int t = threadIdx.x;
    const int lane = t & 63, w = t >> 6;
    const int wm = w >> 1, wn = w & 1;
    const int g = lane >> 4, r16 = lane & 15;
    const int m0 = blockIdx.y * 128, n0 = blockIdx.x * 128;

    f32x4 acc[4][4] = {};

    for (int k0 = 0; k0 < 1024; k0 += 32) {
        __syncthreads();
        #pragma unroll
        for (int i = 0; i < 2; ++i) {
            const int row = i * 64 + (t >> 2);
            const int cl = (t & 3) ^ ((row >> 1) & 3);
            gld16(A  + (size_t)(m0 + row) * 1024 + k0 + cl * 8, Al + i * 2048 + t * 8);
            gld16(Bt + (size_t)(n0 + row) * 1024 + k0 + cl * 8, Bl + i * 2048 + t * 8);
        }
        __syncthreads();

        bf16x8 af[4], bf[4];
        #pragma unroll
        for (int mf = 0; mf < 4; ++mf) {
            const int row = wm * 64 + mf * 16 + r16;
            af[mf] = *reinterpret_cast<const bf16x8*>(
                (const char*)Al + row * 64 + (((g ^ ((row >> 1) & 3))) << 4));
        }
        #pragma unroll
        for (int nf = 0; nf < 4; ++nf) {
            const int row = wn * 64 + nf * 16 + r16;
            bf[nf] = *reinterpret_cast<const bf16x8*>(
                (const char*)Bl + row * 64 + (((g ^ ((row >> 1) & 3))) << 4));
        }
        #pragma unroll
        for (int mf = 0; mf < 4; ++mf)
            #pragma unroll
            for (int nf = 0; nf < 4; ++nf)
                acc[mf][nf] = MFMA(af[mf], bf[nf], acc[mf][nf]);
    }

    #pragma unroll
    for (int nf = 0; nf < 4; ++nf) {
        const int n = n0 + wn * 64 + nf * 16 + r16;
        const int h = n >> 6, dh = n & 63;
        const float bn = bias[n];
        #pragma unroll
        for (int mf = 0; mf < 4; ++mf) {
            #pragma unroll
            for (int r = 0; r < 4; ++r) {
                const int m = m0 + wm * 64 + mf * 16 + 4 * g + r;
                const int bb = m >> 11, l = m & 2047;
                const short val = f2bf(acc[mf][nf][r] + bn);
                if (which < 2)
                    ((which == 0) ? qh : kh)[(((size_t)(bb * H_ + h)) * LQ_ + l) * 64 + dh] = val;
                else
                    vT[(((size_t)(bb * H_ + h)) * 64 + dh) * (size_t)LK_ + l] = val;
            }
        }
    }
}

// ---------------------------------------------------------------------------
// flash: swapped-QK^T MFMA attention.  Block = (b, h, 64 q).  4 waves, each
// owns 16 q.  S^T = mfma(K, Q): lane holds S^T[k=16kb+4g+r][q=lane&15].
// P^T regs feed PV mfma(V^T, P^T) directly (matching k-bijection).
// ---------------------------------------------------------------------------
__global__ __launch_bounds__(256) void flash_kernel(
    const short* __restrict__ qh, const short* __restrict__ kh, const short* __restrict__ vT,
    const float* __restrict__ maskf,
    short* __restrict__ ctx, float* __restrict__ mOut, float* __restrict__ sOut)
{
    const int q0 = blockIdx.x * 64;
    const int h  = blockIdx.y;
    const int b  = blockIdx.z;

    __shared__ short Kl[4096];   // [64 k][64 d] bf16, 16B-chunk-swizzled (^row&7)
    __shared__ short Vl[4096];   // [64 dv][64 k] bf16, same swizzle
    __shared__ float Ml[64];

    const int t = threadIdx.x;
    const int lane = t & 63, w = t >> 6;
    const int g = lane >> 4, q16 = lane & 15;

    const short* kbase = kh + (size_t)(b * H_ + h) * LK_ * 64;
    const short* vbase = vT + (size_t)(b * H_ + h) * 64 * (size_t)LK_;
    const float* mbase = maskf + b * LK_;

    // Q fragments (loop-invariant, from global): d = 32*td + 8g + j
    bf16x8 qf[2];
    {
        const short* qrow = qh + ((size_t)(b * H_ + h) * LQ_ + q0 + w * 16 + q16) * 64;
        qf[0] = *reinterpret_cast<const bf16x8*>(qrow + 8 * g);
        qf[1] = *reinterpret_cast<const bf16x8*>(qrow + 32 + 8 * g);
    }

    f32x4 ot[4] = {};             // O^T frags: dv = 16*fc + 4g + r, q = q16
    float m_run = NEGINF, l_run = 0.f;

    for (int k0 = 0; k0 < LK_; k0 += 64) {
        __syncthreads();
        #pragma unroll
        for (int i = 0; i < 2; ++i) {
            const int row = i * 32 + (t >> 3);
            const int cl = (t & 7) ^ (row & 7);
            gld16(kbase + (size_t)(k0 + row) * 64 + cl * 8, Kl + i * 2048 + t * 8);
            gld16(vbase + (size_t)row * LK_ + k0 + cl * 8, Vl + i * 2048 + t * 8);
        }
        if (t < 64) Ml[t] = mbase[k0 + t];
        __syncthreads();

        // --- QK^T (swapped): S^T[k][q] ---
        float lg[4][4];
        #pragma unroll
        for (int kb = 0; kb < 4; ++kb) {
            const int krow = kb * 16 + q16;
            const char* rowp = (const char*)Kl + krow * 128;
            const int sw = (krow & 7) << 4;
            const bf16x8 kf0 = *reinterpret_cast<const bf16x8*>(rowp + ((g << 4) ^ sw));
            const bf16x8 kf1 = *reinterpret_cast<const bf16x8*>(rowp + (((4 + g) << 4) ^ sw));
            f32x4 s = {};
            s = MFMA(kf0, qf[0], s);
            s = MFMA(kf1, qf[1], s);
            const f32x4 mk = *reinterpret_cast<const f32x4*>(&Ml[kb * 16 + 4 * g]);
            #pragma unroll
            for (int r = 0; r < 4; ++r) lg[kb][r] = s[r] * 0.125f + mk[r];
        }

        // --- online softmax (per q = q16; reduce over k: regs + lanegroups) ---
        float tm = NEGINF;
        #pragma unroll
        for (int kb = 0; kb < 4; ++kb)
            #pragma unroll
            for (int r = 0; r < 4; ++r) tm = fmaxf(tm, lg[kb][r]);
        tm = fmaxf(tm, __shfl_xor(tm, 16));
        tm = fmaxf(tm, __shfl_xor(tm, 32));

        const float m_new = fmaxf(m_run, tm);
        const float alpha = (m_run == NEGINF) ? 0.f : __expf(m_run - m_new);
        const float m_use = (m_new == NEGINF) ? 0.f : m_new;

        float p[4][4];
        float ls = 0.f;
        #pragma unroll
        for (int kb = 0; kb < 4; ++kb)
            #pragma unroll
            for (int r = 0; r < 4; ++r) { p[kb][r] = __expf(lg[kb][r] - m_use); ls += p[kb][r]; }
        ls += __shfl_xor(ls, 16);
        ls += __shfl_xor(ls, 32);
        l_run = l_run * alpha + ls;
        m_run = m_new;

        #pragma unroll
        for (int fc = 0; fc < 4; ++fc)
            #pragma unroll
            for (int r = 0; r < 4; ++r) ot[fc][r] *= alpha;

        // pack P^T to bf16 B-frags: pb[tt][j] = P[k=32tt+4g+(j&3)+16*(j>>2)][q16]
        bf16x8 pb[2];
        #pragma unroll
        for (int r = 0; r < 4; ++r) {
            pb[0][r]     = f2bf(p[0][r]);
            pb[0][4 + r] = f2bf(p[1][r]);
            pb[1][r]     = f2bf(p[2][r]);
            pb[1][4 + r] = f2bf(p[3][r]);
        }

        // --- PV: O^T[dv][q] += mfma(V^T, P^T) ---
        #pragma unroll
        for (int fc = 0; fc < 4; ++fc) {
            const int dvrow = fc * 16 + q16;
            const char* rowp = (const char*)Vl + dvrow * 128;
            const int sw = (dvrow & 7) << 4;
            #pragma unroll
            for (int tt = 0; tt < 2; ++tt) {
                const bf16x4 va = *reinterpret_cast<const bf16x4*>(rowp + ((64 * tt + 8 * g) ^ sw));
                const bf16x4 vb = *reinterpret_cast<const bf16x4*>(rowp + ((64 * tt + 32 + 8 * g) ^ sw));
                bf16x8 af;
                af[0] = va[0]; af[1] = va[1]; af[2] = va[2]; af[3] = va[3];
                af[4] = vb[0]; af[5] = vb[1]; af[6] = vb[2]; af[7] = vb[3];
                ot[fc] = MFMA(af, pb[tt], ot[fc]);
            }
        }
    }

    const float rs = (l_run > 0.f) ? 1.0f / l_run : 0.f;
    short* crow = ctx + ((size_t)b * LQ_ + q0 + w * 16 + q16) * (size_t)(H_ * 64) + h * 64;
    #pragma unroll
    for (int fc = 0; fc < 4; ++fc) {
        bf16x4 o4;
        #pragma unroll
        for (int r = 0; r < 4; ++r) o4[r] = f2bf(ot[fc][r] * rs);
        *reinterpret_cast<bf16x4*>(crow + fc * 16 + 4 * g) = o4;
    }
    if (lane < 16) {
        const size_t idx = (size_t)(b * H_ + h) * LQ_ + q0 + w * 16 + lane;
        mOut[idx] = m_run;
        sOut[idx] = l_run;
    }
}

// ---------------------------------------------------------------------------
// avg: attn_avg[b][q][k] = (1/H) sum_h exp(l_h - m_h)/s_h.  Same fragments /
// MFMA as flash -> logits bit-identical to the saved stats.
// ---------------------------------------------------------------------------
__global__ __launch_bounds__(256) void avg_kernel(
    const short* __restrict__ qh, const short* __restrict__ kh,
    const float* __restrict__ maskf,
    const float* __restrict__ mS, const float* __restrict__ sS,
    float* __restrict__ attn_avg)
{
    const int k0 = blockIdx.x * 64;
    const int q0 = blockIdx.y * 64;
    const int b  = blockIdx.z;

    __shared__ short Kl[4096];
    __shared__ float Ml[64];

    const int t = threadIdx.x;
    const int lane = t & 63, w = t >> 6;
    const int g = lane >> 4, q16 = lane & 15;

    if (t < 64) Ml[t] = maskf[b * LK_ + k0 + t];
    __syncthreads();
    f32x4 mk[4];
    #pragma unroll
    for (int kb = 0; kb < 4; ++kb) mk[kb] = *reinterpret_cast<const f32x4*>(&Ml[kb * 16 + 4 * g]);

    f32x4 acc[4] = {};

    for (int h = 0; h < H_; ++h) {
        __syncthreads();
        #pragma unroll
        for (int i = 0; i < 2; ++i) {
            const int row = i * 32 + (t >> 3);
            const int cl = (t & 7) ^ (row & 7);
            gld16(kh + (size_t)(b * H_ + h) * LK_ * 64 + (size_t)(k0 + row) * 64 + cl * 8,
                  Kl + i * 2048 + t * 8);
        }
        __syncthreads();

        const short* qrow = qh + ((size_t)(b * H_ + h) * LQ_ + q0 + w * 16 + q16) * 64;
        const bf16x8 qf0 = *reinterpret_cast<const bf16x8*>(qrow + 8 * g);
        const bf16x8 qf1 = *reinterpret_cast<const bf16x8*>(qrow + 32 + 8 * g);

        const size_t sidx = (size_t)(b * H_ + h) * LQ_ + q0 + w * 16 + q16;
        const float mrow = mS[sidx], srow = sS[sidx];
        const float valid = (mrow == NEGINF || srow <= 0.f) ? 0.f : 1.0f / srow;
        const float m_use = (mrow == NEGINF) ? 0.f : mrow;

        #pragma unroll
        for (int kb = 0; kb < 4; ++kb) {
            const int krow = kb * 16 + q16;
            const char* rowp = (const char*)Kl + krow * 128;
            const int sw = (krow & 7) << 4;
            const bf16x8 kf0 = *reinterpret_cast<const bf16x8*>(rowp + ((g << 4) ^ sw));
            const bf16x8 kf1 = *reinterpret_cast<const bf16x8*>(rowp + (((4 + g) << 4) ^ sw));
            f32x4 s = {};
            s = MFMA(kf0, qf0, s);
            s = MFMA(kf1, qf1, s);
            #pragma unroll
            for (int r = 0; r < 4; ++r) {
                const float lgv = s[r] * 0.125f + mk[kb][r];
                acc[kb][r] += __expf(lgv - m_use) * valid;
            }
        }
    }

    const float sc = 1.0f / (float)H_;
    float* orow = attn_avg + ((size_t)b * LQ_ + q0 + w * 16 + q16) * (size_t)LK_ + k0;
    #pragma unroll
    for (int kb = 0; kb < 4; ++kb) {
        f32x4 o = acc[kb];
        o[0] *= sc; o[1] *= sc; o[2] *= sc; o[3] *= sc;
        *reinterpret_cast<f32x4*>(orow + kb * 16 + 4 * g) = o;
    }
}

// ---------------------------------------------------------------------------
// outproj: preln = ctx(bf16) @ WoT^T + bo + resid.  Same GEMM as proj.
// ---------------------------------------------------------------------------
__global__ __launch_bounds__(256) void outproj_kernel(
    const short* __restrict__ ctxIn, const short* __restrict__ Wto,
    const float* __restrict__ bo, const float* __restrict__ resid,
    float* __restrict__ preln)
{
    __shared__ short Al[4096];
    __shared__ short Bl[4096];

    const int t = threadIdx.x;
    const int lane = t & 63, w = t >> 6;
    const int wm = w >> 1, wn = w & 1;
    const int g = lane >> 4, r16 = lane & 15;
    const int m0 = blockIdx.y * 128, n0 = blockIdx.x * 128;

    f32x4 acc[4][4] = {};

    for (int k0 = 0; k0 < 1024; k0 += 32) {
        __syncthreads();
        #pragma unroll
        for (int i = 0; i < 2; ++i) {
            const int row = i * 64 + (t >> 2);
            const int cl = (t & 3) ^ ((row >> 1) & 3);
            gld16(ctxIn + (size_t)(m0 + row) * 1024 + k0 + cl * 8, Al + i * 2048 + t * 8);
            gld16(Wto   + (size_t)(n0 + row) * 1024 + k0 + cl * 8, Bl + i * 2048 + t * 8);
        }
        __syncthreads();

        bf16x8 af[4], bf[4];
        #pragma unroll
        for (int mf = 0; mf < 4; ++mf) {
            const int row = wm * 64 + mf * 16 + r16;
            af[mf] = *reinterpret_cast<const bf16x8*>(
                (const char*)Al + row * 64 + (((g ^ ((row >> 1) & 3))) << 4));
        }
        #pragma unroll
        for (int nf = 0; nf < 4; ++nf) {
            const int row = wn * 64 + nf * 16 + r16;
            bf[nf] = *reinterpret_cast<const bf16x8*>(
                (const char*)Bl + row * 64 + (((g ^ ((row >> 1) & 3))) << 4));
        }
        #pragma unroll
        for (int mf = 0; mf < 4; ++mf)
            #pragma unroll
            for (int nf = 0; nf < 4; ++nf)
                acc[mf][nf] = MFMA(af[mf], bf[nf], acc[mf][nf]);
    }

    #pragma unroll
    for (int nf = 0; nf < 4; ++nf) {
        const int n = n0 + wn * 64 + nf * 16 + r16;
        const float bn = bo[n];
        #pragma unroll
        for (int mf = 0; mf < 4; ++mf) {
            #pragma unroll
            for (int r = 0; r < 4; ++r) {
                const size_t m = m0 + wm * 64 + mf * 16 + 4 * g + r;
                preln[m * 1024 + n] = acc[mf][nf][r] + bn + resid[m * 1024 + n];
            }
        }
    }
}

// ---------------------------------------------------------------------------
// ln: LayerNorm over D=1024, one block per row.
// ---------------------------------------------------------------------------
__global__ __launch_bounds__(256) void ln_kernel(
    const float* __restrict__ xin, const float* __restrict__ gam,
    const float* __restrict__ bet, float* __restrict__ out)
{
    const size_t row = blockIdx.x;
    const int t = threadIdx.x;
    const float4 v = *reinterpret_cast<const float4*>(&xin[row * 1024 + t * 4]);

    float s  = v.x + v.y + v.z + v.w;
    float ss = v.x * v.x + v.y * v.y + v.z * v.z + v.w * v.w;
    #pragma unroll
    for (int w = 1; w < 64; w <<= 1) { s += __shfl_xor(s, w); ss += __shfl_xor(ss, w); }

    __shared__ float rs_[4], rss_[4];
    if ((t & 63) == 0) { rs_[t >> 6] = s; rss_[t >> 6] = ss; }
    __syncthreads();
    s  = rs_[0] + rs_[1] + rs_[2] + rs_[3];
    ss = rss_[0] + rss_[1] + rss_[2] + rss_[3];

    const float mean = s * (1.0f / 1024.0f);
    const float var  = ss * (1.0f / 1024.0f) - mean * mean;
    const float rstd = rsqrtf(var + LN_EPS_);

    const float4 g4 = *reinterpret_cast<const float4*>(&gam[t * 4]);
    const float4 b4 = *reinterpret_cast<const float4*>(&bet[t * 4]);
    float4 o;
    o.x = (v.x - mean) * rstd * g4.x + b4.x;
    o.y = (v.y - mean) * rstd * g4.y + b4.y;
    o.z = (v.z - mean) * rstd * g4.z + b4.z;
    o.w = (v.w - mean) * rstd * g4.w + b4.w;
    *reinterpret_cast<float4*>(&out[row * 1024 + t * 4]) = o;
}

// ---------------------------------------------------------------------------
extern "C" void kernel_launch(void* const* d_in, const int* in_sizes, int n_in,
                              void* d_out, int out_size, void* d_ws, size_t ws_size,
                              hipStream_t stream)
{
    const float* q    = (const float*)d_in[0];
    const float* k    = (const float*)d_in[1];
    const float* v    = (const float*)d_in[2];
    const int*   mask = (const int*)d_in[3];
    const float* Wq   = (const float*)d_in[4];
    const float* bq   = (const float*)d_in[5];
    const float* Wk   = (const float*)d_in[6];
    const float* bk   = (const float*)d_in[7];
    const float* Wv   = (const float*)d_in[8];
    const float* bv   = (const float*)d_in[9];
    const float* Wo   = (const float*)d_in[10];
    const float* bo   = (const float*)d_in[11];
    const float* lng  = (const float*)d_in[12];
    const float* lnb  = (const float*)d_in[13];

    float* out      = (float*)d_out;                    // [B,LQ,D]
    float* attn_avg = out + (size_t)B_ * LQ_ * D_;      // [B,LQ,LK]

    const size_t XSZ = (size_t)B_ * LQ_ * D_;           // 8388608 elements
    const size_t WSZ = (size_t)D_ * D_;                 // 1048576

    short* Xq  = (short*)d_ws;
    short* Xk  = Xq + XSZ;
    short* Xv  = Xk + XSZ;
    short* Wtq = Xv + XSZ;
    short* Wtk = Wtq + WSZ;
    short* Wtv = Wtk + WSZ;
    short* Wto = Wtv + WSZ;
    short* qh  = Wto + WSZ;                             // [B,H,LQ,64] bf16
    short* kh  = qh + XSZ;
    short* vT  = kh + XSZ;                              // [B,H,64,LK] bf16
    float* mSt = (float*)(vT + XSZ);                    // [B,H,LQ]
    float* sSt = mSt + (size_t)B_ * H_ * LQ_;
    float* maskf = sSt + (size_t)B_ * H_ * LQ_;         // [B,LK]
    float* preln = (float*)d_ws;                        // overlays Xq+Xk (dead after proj)
    short* ctx   = Xv;                                  // overlays Xv (dead after proj)

    cast_x_kernel<<<dim3(4096, 3), 256, 0, stream>>>(q, k, v, mask, Xq, Xk, Xv, maskf);
    cast_wt_kernel<<<dim3(16, 16, 4), 256, 0, stream>>>(Wq, Wk, Wv, Wo, Wtq, Wtk, Wtv, Wto);

    proj_kernel<<<dim3(8, 64, 3), 256, 0, stream>>>(Xq, Xk, Xv, Wtq, Wtk, Wtv,
                                                    bq, bk, bv, qh, kh, vT);

    flash_kernel<<<dim3(32, 16, 4), 256, 0, stream>>>(qh, kh, vT, maskf, ctx, mSt, sSt);

    avg_kernel<<<dim3(32, 32, 4), 256, 0, stream>>>(qh, kh, maskf, mSt, sSt, attn_avg);

    outproj_kernel<<<dim3(8, 64), 256, 0, stream>>>(ctx, Wto, bo, q, preln);

    ln_kernel<<<8192, 256, 0, stream>>>(preln, lng, lnb, out);
}

// Round 3
// 388.450 us; speedup vs baseline: 10.3386x; 1.0549x over previous
//
#include <hip/hip_runtime.h>
#include <hip/hip_bf16.h>
#include <math.h>

#define B_    4
#define LQ_   2048
#define LK_   2048
#define D_    1024
#define H_    16
#define LN_EPS_ 1e-5f
#define NEGINF (-__builtin_inff())
#define QSCALE 0.18033688011112042f   // log2(e)/8 — folded into qh at proj

typedef __attribute__((ext_vector_type(8))) short bf16x8;
typedef __attribute__((ext_vector_type(4))) short bf16x4;
typedef __attribute__((ext_vector_type(4))) float f32x4;

#define MFMA(a, b, c) __builtin_amdgcn_mfma_f32_16x16x32_bf16(a, b, c, 0, 0, 0)

#if __has_builtin(__builtin_amdgcn_exp2f)
#define EXP2(x) __builtin_amdgcn_exp2f(x)
#else
#define EXP2(x) __expf((x) * 0.6931471805599453f)
#endif

__device__ __forceinline__ short f2bf(float f) {
    union { __hip_bfloat16 h; short s; } u;
    u.h = __float2bfloat16(f);
    return u.s;
}

__device__ __forceinline__ void gld16(const short* g, short* l) {
    __builtin_amdgcn_global_load_lds(
        (const __attribute__((address_space(1))) void*)g,
        (__attribute__((address_space(3))) void*)l, 16, 0, 0);
}

// ---------------------------------------------------------------------------
// cast_x: f32 -> bf16 straight copy of q/k/v; also builds additive mask.
// ---------------------------------------------------------------------------
__global__ __launch_bounds__(256) void cast_x_kernel(
    const float* __restrict__ q, const float* __restrict__ k, const float* __restrict__ v,
    const int* __restrict__ mask,
    short* __restrict__ Xq, short* __restrict__ Xk, short* __restrict__ Xv,
    float* __restrict__ maskf)
{
    const int which = blockIdx.y;
    const float* src = which == 0 ? q : (which == 1 ? k : v);
    short* dst       = which == 0 ? Xq : (which == 1 ? Xk : Xv);
    const int t = threadIdx.x;
    const size_t i = ((size_t)blockIdx.x * 256 + t) * 8;
    const float4 a = *reinterpret_cast<const float4*>(src + i);
    const float4 c = *reinterpret_cast<const float4*>(src + i + 4);
    bf16x8 o;
    o[0] = f2bf(a.x); o[1] = f2bf(a.y); o[2] = f2bf(a.z); o[3] = f2bf(a.w);
    o[4] = f2bf(c.x); o[5] = f2bf(c.y); o[6] = f2bf(c.z); o[7] = f2bf(c.w);
    *reinterpret_cast<bf16x8*>(dst + i) = o;
    if (which == 0) {
        const int gid = blockIdx.x * 256 + t;
        if (gid < B_ * LK_) maskf[gid] = (mask[gid] != 0) ? NEGINF : 0.0f;
    }
}

// ---------------------------------------------------------------------------
// cast_wt: W[k][n] f32 -> Wt[n][k] bf16 (transposed), 64x64 LDS tiles.
// ---------------------------------------------------------------------------
__global__ __launch_bounds__(256) void cast_wt_kernel(
    const float* __restrict__ Wq, const float* __restrict__ Wk,
    const float* __restrict__ Wv, const float* __restrict__ Wo,
    short* __restrict__ Wtq, short* __restrict__ Wtk,
    short* __restrict__ Wtv, short* __restrict__ Wto)
{
    const int which = blockIdx.z;
    const float* W = which == 0 ? Wq : (which == 1 ? Wk : (which == 2 ? Wv : Wo));
    short* Wt      = which == 0 ? Wtq : (which == 1 ? Wtk : (which == 2 ? Wtv : Wto));

    __shared__ float T[64][65];
    const int t = threadIdx.x;
    const int k0 = blockIdx.x * 64, n0 = blockIdx.y * 64;
    {
        const int row = t >> 2, cq = (t & 3) * 16;
        #pragma unroll
        for (int i = 0; i < 4; ++i) {
            const float4 v4 = *reinterpret_cast<const float4*>(&W[(size_t)(k0 + row) * 1024 + n0 + cq + i * 4]);
            T[row][cq + i * 4 + 0] = v4.x; T[row][cq + i * 4 + 1] = v4.y;
            T[row][cq + i * 4 + 2] = v4.z; T[row][cq + i * 4 + 3] = v4.w;
        }
    }
    __syncthreads();
    const int nl = t >> 2, kq = (t & 3) * 16;
    bf16x8 o0, o1;
    #pragma unroll
    for (int j = 0; j < 8; ++j) {
        o0[j] = f2bf(T[kq + j][nl]);
        o1[j] = f2bf(T[kq + 8 + j][nl]);
    }
    *reinterpret_cast<bf16x8*>(&Wt[(size_t)(n0 + nl) * 1024 + k0 + kq]) = o0;
    *reinterpret_cast<bf16x8*>(&Wt[(size_t)(n0 + nl) * 1024 + k0 + kq + 8]) = o1;
}

// ---------------------------------------------------------------------------
// proj: C = X(bf16)[M=8192,K=1024] @ Wt^T + bias.  128x128 tile, BK=32.
// which: 0->qh (scaled by log2e/8 for base-2 softmax), 1->kh, 2->vT.
// ---------------------------------------------------------------------------
__global__ __launch_bounds__(256) void proj_kernel(
    const short* __restrict__ Xq, const short* __restrict__ Xk, const short* __restrict__ Xv,
    const short* __restrict__ Wtq, const short* __restrict__ Wtk, const short* __restrict__ Wtv,
    const float* __restrict__ bq, const float* __restrict__ bk, const float* __restrict__ bv,
    short* __restrict__ qh, short* __restrict__ kh, short* __restrict__ vT)
{
    const int which = blockIdx.z;
    const short* A  = which == 0 ? Xq : (which == 1 ? Xk : Xv);
    const short* Bt = which == 0 ? Wtq : (which == 1 ? Wtk : Wtv);
    const float* bias = which == 0 ? bq : (which == 1 ? bk : bv);

    __shared__ short Al[4096];   // [128 rows m][32 k], swizzled chunks
    __shared__ short Bl[4096];   // [128 rows n][32 k], swizzled chunks

    const int t = threadIdx.x;
    const int lane = t & 63, w = t >> 6;
    const int wm = w >> 1, wn = w & 1;
    const int g = lane >> 4, r16 = lane & 15;
    const int m0 = blockIdx.y * 128, n0 = blockIdx.x * 128;

    f32x4 acc[4][4] = {};

    for (int k0 = 0; k0 < 1024; k0 += 32) {
        __syncthreads();
        #pragma unroll
        for (int i = 0; i < 2; ++i) {
            const int row = i * 64 + (t >> 2);
            const int cl = (t & 3) ^ ((row >> 1) & 3);
            gld16(A  + (size_t)(m0 + row) * 1024 + k0 + cl * 8, Al + i * 2048 + t * 8);
            gld16(Bt + (size_t)(n0 + row) * 1024 + k0 + cl * 8, Bl + i * 2048 + t * 8);
        }
        __syncthreads();

        bf16x8 af[4], bf[4];
        #pragma unroll
        for (int mf = 0; mf < 4; ++mf) {
            const int row = wm * 64 + mf * 16 + r16;
            af[mf] = *reinterpret_cast<const bf16x8*>(
                (const char*)Al + row * 64 + (((g ^ ((row >> 1) & 3))) << 4));
        }
        #pragma unroll
        for (int nf = 0; nf < 4; ++nf) {
            const int row = wn * 64 + nf * 16 + r16;
            bf[nf] = *reinterpret_cast<const bf16x8*>(
                (const char*)Bl + row * 64 + (((g ^ ((row >> 1) & 3))) << 4));
        }
        #pragma unroll
        for (int mf = 0; mf < 4; ++mf)
            #pragma unroll
            for (int nf = 0; nf < 4; ++nf)
                acc[mf][nf] = MFMA(af[mf], bf[nf], acc[mf][nf]);
    }

    #pragma unroll
    for (int nf = 0; nf < 4; ++nf) {
        const int n = n0 + wn * 64 + nf * 16 + r16;
        const int h = n >> 6, dh = n & 63;
        const float bn = bias[n];
        #pragma unroll
        for (int mf = 0; mf < 4; ++mf) {
            #pragma unroll
            for (int r = 0; r < 4; ++r) {
                const int m = m0 + wm * 64 + mf * 16 + 4 * g + r;
                const int bb = m >> 11, l = m & 2047;
                float vf = acc[mf][nf][r] + bn;
                if (which == 0) vf *= QSCALE;       // base-2 logit domain
                const short val = f2bf(vf);
                if (which < 2)
                    ((which == 0) ? qh : kh)[(((size_t)(bb * H_ + h)) * LQ_ + l) * 64 + dh] = val;
                else
                    vT[(((size_t)(bb * H_ + h)) * 64 + dh) * (size_t)LK_ + l] = val;
            }
        }
    }
}

// ---------------------------------------------------------------------------
// flash: swapped-QK^T MFMA attention, 2-phase double-buffered staging.
// Block = (b, h, 64 q).  4 waves x 16 q.  Mask row resident in LDS, folded
// into the MFMA C-operand.  Base-2 softmax with defer-rescale (THR=8).
// ---------------------------------------------------------------------------
__global__ __launch_bounds__(256) void flash_kernel(
    const short* __restrict__ qh, const short* __restrict__ kh, const short* __restrict__ vT,
    const float* __restrict__ maskf,
    short* __restrict__ ctx, float* __restrict__ mOut, float* __restrict__ sOut)
{
    const int q0 = blockIdx.x * 64;
    const int h  = blockIdx.y;
    const int b  = blockIdx.z;

    __shared__ short Kl[2][4096];   // [64 k][64 d] bf16, 16B-chunk swizzle (^row&7)
    __shared__ short Vl[2][4096];   // [64 dv][64 k] bf16, same swizzle
    __shared__ float Mrow[2048];    // full additive-mask row for this b

    const int t = threadIdx.x;
    const int lane = t & 63, w = t >> 6;
    const int g = lane >> 4, q16 = lane & 15;

    const short* kbase = kh + (size_t)(b * H_ + h) * LK_ * 64;
    const short* vbase = vT + (size_t)(b * H_ + h) * 64 * (size_t)LK_;

    {   // one-time: stage whole mask row (8 KB)
        const float* mb = maskf + b * LK_;
        const int o = t * 8;
        *reinterpret_cast<f32x4*>(&Mrow[o])     = *reinterpret_cast<const f32x4*>(mb + o);
        *reinterpret_cast<f32x4*>(&Mrow[o + 4]) = *reinterpret_cast<const f32x4*>(mb + o + 4);
    }

    // Q fragments (loop-invariant): pre-scaled by log2e/8 at proj time
    bf16x8 qf0, qf1;
    {
        const short* qrow = qh + ((size_t)(b * H_ + h) * LQ_ + q0 + w * 16 + q16) * 64;
        qf0 = *reinterpret_cast<const bf16x8*>(qrow + 8 * g);
        qf1 = *reinterpret_cast<const bf16x8*>(qrow + 32 + 8 * g);
    }

    const int srw = t >> 3, scl = t & 7;

    f32x4 ot[4] = {};             // O^T frags: dv = 16*fc + 4g + r, q = q16
    float m_run = NEGINF, l_run = 0.f;

    {   // prologue: stage tile 0 into buf 0
        #pragma unroll
        for (int i = 0; i < 2; ++i) {
            const int row = i * 32 + srw;
            const int cl = scl ^ (row & 7);
            gld16(kbase + (size_t)row * 64 + cl * 8, Kl[0] + i * 2048 + t * 8);
            gld16(vbase + (size_t)row * LK_ + cl * 8, Vl[0] + i * 2048 + t * 8);
        }
    }
    __syncthreads();

    int cur = 0;
    for (int k0 = 0; k0 < LK_; k0 += 64) {
        // issue next tile's staging (drained by the end-of-iter barrier)
        if (k0 + 64 < LK_) {
            const int kn = k0 + 64;
            #pragma unroll
            for (int i = 0; i < 2; ++i) {
                const int row = i * 32 + srw;
                const int cl = scl ^ (row & 7);
                gld16(kbase + (size_t)(kn + row) * 64 + cl * 8, Kl[cur ^ 1] + i * 2048 + t * 8);
                gld16(vbase + (size_t)row * LK_ + kn + cl * 8, Vl[cur ^ 1] + i * 2048 + t * 8);
            }
        }

        // --- QK^T (swapped): S^T[k][q], mask folded into C-init ---
        float lg[4][4];
        const short* klp = Kl[cur];
        __builtin_amdgcn_s_setprio(1);
        #pragma unroll
        for (int kb = 0; kb < 4; ++kb) {
            const int krow = kb * 16 + q16;
            const char* rowp = (const char*)klp + krow * 128;
            const int sw = (krow & 7) << 4;
            const bf16x8 kf0 = *reinterpret_cast<const bf16x8*>(rowp + ((g << 4) ^ sw));
            const bf16x8 kf1 = *reinterpret_cast<const bf16x8*>(rowp + (((4 + g) << 4) ^ sw));
            f32x4 s = *reinterpret_cast<const f32x4*>(&Mrow[k0 + kb * 16 + 4 * g]);
            s = MFMA(kf0, qf0, s);
            s = MFMA(kf1, qf1, s);
            #pragma unroll
            for (int r = 0; r < 4; ++r) lg[kb][r] = s[r];
        }
        __builtin_amdgcn_s_setprio(0);

        // --- online softmax (base-2), defer-rescale THR=8 ---
        float tm = NEGINF;
        #pragma unroll
        for (int kb = 0; kb < 4; ++kb)
            #pragma unroll
            for (int r = 0; r < 4; ++r) tm = fmaxf(tm, lg[kb][r]);
        tm = fmaxf(tm, __shfl_xor(tm, 16));
        tm = fmaxf(tm, __shfl_xor(tm, 32));

        const bool skip = __all(tm <= m_run + 8.0f);
        if (!skip) {
            const float m_new = fmaxf(m_run, tm);
            const float alpha = (m_run == NEGINF) ? 0.f : EXP2(m_run - m_new);
            #pragma unroll
            for (int fc = 0; fc < 4; ++fc)
                #pragma unroll
                for (int r = 0; r < 4; ++r) ot[fc][r] *= alpha;
            l_run *= alpha;
            m_run = m_new;
        }
        const float m_use = (m_run == NEGINF) ? 0.f : m_run;

        float p[4][4];
        float ls = 0.f;
        #pragma unroll
        for (int kb = 0; kb < 4; ++kb)
            #pragma unroll
            for (int r = 0; r < 4; ++r) { p[kb][r] = EXP2(lg[kb][r] - m_use); ls += p[kb][r]; }
        ls += __shfl_xor(ls, 16);
        ls += __shfl_xor(ls, 32);
        l_run += ls;

        // pack P^T to bf16 B-frags (k-bijection matches V^T A-frags)
        bf16x8 pb[2];
        #pragma unroll
        for (int r = 0; r < 4; ++r) {
            pb[0][r]     = f2bf(p[0][r]);
            pb[0][4 + r] = f2bf(p[1][r]);
            pb[1][r]     = f2bf(p[2][r]);
            pb[1][4 + r] = f2bf(p[3][r]);
        }

        // --- PV: O^T[dv][q] += mfma(V^T, P^T) ---
        const short* vlp = Vl[cur];
        __builtin_amdgcn_s_setprio(1);
        #pragma unroll
        for (int fc = 0; fc < 4; ++fc) {
            const int dvrow = fc * 16 + q16;
            const char* rowp = (const char*)vlp + dvrow * 128;
            const int sw = (dvrow & 7) << 4;
            #pragma unroll
            for (int tt = 0; tt < 2; ++tt) {
                const bf16x4 va = *reinterpret_cast<const bf16x4*>(rowp + ((64 * tt + 8 * g) ^ sw));
                const bf16x4 vb = *reinterpret_cast<const bf16x4*>(rowp + ((64 * tt + 32 + 8 * g) ^ sw));
                bf16x8 af;
                af[0] = va[0]; af[1] = va[1]; af[2] = va[2]; af[3] = va[3];
                af[4] = vb[0]; af[5] = vb[1]; af[6] = vb[2]; af[7] = vb[3];
                ot[fc] = MFMA(af, pb[tt], ot[fc]);
            }
        }
        __builtin_amdgcn_s_setprio(0);

        __syncthreads();   // drains next-tile gld16s; next iter reads cur^1
        cur ^= 1;
    }

    const float rs = (l_run > 0.f) ? 1.0f / l_run : 0.f;
    short* crow = ctx + ((size_t)b * LQ_ + q0 + w * 16 + q16) * (size_t)(H_ * 64) + h * 64;
    #pragma unroll
    for (int fc = 0; fc < 4; ++fc) {
        bf16x4 o4;
        #pragma unroll
        for (int r = 0; r < 4; ++r) o4[r] = f2bf(ot[fc][r] * rs);
        *reinterpret_cast<bf16x4*>(crow + fc * 16 + 4 * g) = o4;
    }
    if (lane < 16) {
        const size_t idx = (size_t)(b * H_ + h) * LQ_ + q0 + w * 16 + lane;
        mOut[idx] = m_run;
        sOut[idx] = l_run;
    }
}

// ---------------------------------------------------------------------------
// avg: attn_avg[b][q][k] = (1/H) sum_h exp2(l2_h - m2_h)/s_h.  Same fragments
// and MFMA order as flash -> bit-identical logits.  Head-loop double-buffer.
// ---------------------------------------------------------------------------
__global__ __launch_bounds__(256) void avg_kernel(
    const short* __restrict__ qh, const short* __restrict__ kh,
    const float* __restrict__ maskf,
    const float* __restrict__ mS, const float* __restrict__ sS,
    float* __restrict__ attn_avg)
{
    const int k0 = blockIdx.x * 64;
    const int q0 = blockIdx.y * 64;
    const int b  = blockIdx.z;

    __shared__ short Kl[2][4096];

    const int t = threadIdx.x;
    const int lane = t & 63, w = t >> 6;
    const int g = lane >> 4, q16 = lane & 15;

    f32x4 mk[4];
    #pragma unroll
    for (int kb = 0; kb < 4; ++kb)
        mk[kb] = *reinterpret_cast<const f32x4*>(maskf + b * LK_ + k0 + kb * 16 + 4 * g);

    const int srw = t >> 3, scl = t & 7;
    const size_t khbase = (size_t)b * H_ * (size_t)LK_ * 64;

    const short* qbase = qh + ((size_t)b * H_ * LQ_ + q0 + w * 16 + q16) * 64;  // h-stride LQ_*64
    const size_t stbase = (size_t)b * H_ * LQ_ + q0 + w * 16 + q16;             // h-stride LQ_

    {   // prologue: stage head 0
        #pragma unroll
        for (int i = 0; i < 2; ++i) {
            const int row = i * 32 + srw;
            const int cl = scl ^ (row & 7);
            gld16(kh + khbase + (size_t)(k0 + row) * 64 + cl * 8, Kl[0] + i * 2048 + t * 8);
        }
    }
    bf16x8 qf0 = *reinterpret_cast<const bf16x8*>(qbase + 8 * g);
    bf16x8 qf1 = *reinterpret_cast<const bf16x8*>(qbase + 32 + 8 * g);
    float mrow = mS[stbase], srv = sS[stbase];
    __syncthreads();

    f32x4 acc[4] = {};
    int cur = 0;
    for (int hh = 0; hh < H_; ++hh) {
        bf16x8 qn0, qn1; float mn = 0.f, sn = 0.f;
        if (hh + 1 < H_) {
            #pragma unroll
            for (int i = 0; i < 2; ++i) {
                const int row = i * 32 + srw;
                const int cl = scl ^ (row & 7);
                gld16(kh + khbase + (size_t)(hh + 1) * LK_ * 64 + (size_t)(k0 + row) * 64 + cl * 8,
                      Kl[cur ^ 1] + i * 2048 + t * 8);
            }
            const short* qb2 = qbase + (size_t)(hh + 1) * LQ_ * 64;
            qn0 = *reinterpret_cast<const bf16x8*>(qb2 + 8 * g);
            qn1 = *reinterpret_cast<const bf16x8*>(qb2 + 32 + 8 * g);
            mn = mS[stbase + (size_t)(hh + 1) * LQ_];
            sn = sS[stbase + (size_t)(hh + 1) * LQ_];
        }

        const float valid = (mrow == NEGINF || srv <= 0.f) ? 0.f : 1.0f / srv;
        const float m_use = (mrow == NEGINF) ? 0.f : mrow;

        const short* klp = Kl[cur];
        __builtin_amdgcn_s_setprio(1);
        #pragma unroll
        for (int kb = 0; kb < 4; ++kb) {
            const int krow = kb * 16 + q16;
            const char* rowp = (const char*)klp + krow * 128;
            const int sw = (krow & 7) << 4;
            const bf16x8 kf0 = *reinterpret_cast<const bf16x8*>(rowp + ((g << 4) ^ sw));
            const bf16x8 kf1 = *reinterpret_cast<const bf16x8*>(rowp + (((4 + g) << 4) ^ sw));
            f32x4 s = mk[kb];
            s = MFMA(kf0, qf0, s);
            s = MFMA(kf1, qf1, s);
            #pragma unroll
            for (int r = 0; r < 4; ++r)
                acc[kb][r] += EXP2(s[r] - m_use) * valid;
        }
        __builtin_amdgcn_s_setprio(0);

        __syncthreads();
        if (hh + 1 < H_) { qf0 = qn0; qf1 = qn1; mrow = mn; srv = sn; }
        cur ^= 1;
    }

    const float sc = 1.0f / (float)H_;
    float* orow = attn_avg + ((size_t)b * LQ_ + q0 + w * 16 + q16) * (size_t)LK_ + k0;
    #pragma unroll
    for (int kb = 0; kb < 4; ++kb) {
        f32x4 o = acc[kb];
        o[0] *= sc; o[1] *= sc; o[2] *= sc; o[3] *= sc;
        *reinterpret_cast<f32x4*>(orow + kb * 16 + 4 * g) = o;
    }
}

// ---------------------------------------------------------------------------
// outproj: preln = ctx(bf16) @ WoT^T + bo + resid.
// ---------------------------------------------------------------------------
__global__ __launch_bounds__(256) void outproj_kernel(
    const short* __restrict__ ctxIn, const short* __restrict__ Wto,
    const float* __restrict__ bo, const float* __restrict__ resid,
    float* __restrict__ preln)
{
    __shared__ short Al[4096];
    __shared__ short Bl[4096];

    const int t = threadIdx.x;
    const int lane = t & 63, w = t >> 6;
    const int wm = w >> 1, wn = w & 1;
    const int g = lane >> 4, r16 = lane & 15;
    const int m0 = blockIdx.y * 128, n0 = blockIdx.x * 128;

    f32x4 acc[4][4] = {};

    for (int k0 = 0; k0 < 1024; k0 += 32) {
        __syncthreads();
        #pragma unroll
        for (int i = 0; i < 2; ++i) {
            const int row = i * 64 + (t >> 2);
            const int cl = (t & 3) ^ ((row >> 1) & 3);
            gld16(ctxIn + (size_t)(m0 + row) * 1024 + k0 + cl * 8, Al + i * 2048 + t * 8);
            gld16(Wto   + (size_t)(n0 + row) * 1024 + k0 + cl * 8, Bl + i * 2048 + t * 8);
        }
        __syncthreads();

        bf16x8 af[4], bf[4];
        #pragma unroll
        for (int mf = 0; mf < 4; ++mf) {
            const int row = wm * 64 + mf * 16 + r16;
            af[mf] = *reinterpret_cast<const bf16x8*>(
                (const char*)Al + row * 64 + (((g ^ ((row >> 1) & 3))) << 4));
        }
        #pragma unroll
        for (int nf = 0; nf < 4; ++nf) {
            const int row = wn * 64 + nf * 16 + r16;
            bf[nf] = *reinterpret_cast<const bf16x8*>(
                (const char*)Bl + row * 64 + (((g ^ ((row >> 1) & 3))) << 4));
        }
        #pragma unroll
        for (int mf = 0; mf < 4; ++mf)
            #pragma unroll
            for (int nf = 0; nf < 4; ++nf)
                acc[mf][nf] = MFMA(af[mf], bf[nf], acc[mf][nf]);
    }

    #pragma unroll
    for (int nf = 0; nf < 4; ++nf) {
        const int n = n0 + wn * 64 + nf * 16 + r16;
        const float bn = bo[n];
        #pragma unroll
        for (int mf = 0; mf < 4; ++mf) {
            #pragma unroll
            for (int r = 0; r < 4; ++r) {
                const size_t m = m0 + wm * 64 + mf * 16 + 4 * g + r;
                preln[m * 1024 + n] = acc[mf][nf][r] + bn + resid[m * 1024 + n];
            }
        }
    }
}

// ---------------------------------------------------------------------------
// ln: LayerNorm over D=1024, one block per row.
// ---------------------------------------------------------------------------
__global__ __launch_bounds__(256) void ln_kernel(
    const float* __restrict__ xin, const float* __restrict__ gam,
    const float* __restrict__ bet, float* __restrict__ out)
{
    const size_t row = blockIdx.x;
    const int t = threadIdx.x;
    const float4 v = *reinterpret_cast<const float4*>(&xin[row * 1024 + t * 4]);

    float s  = v.x + v.y + v.z + v.w;
    float ss = v.x * v.x + v.y * v.y + v.z * v.z + v.w * v.w;
    #pragma unroll
    for (int w = 1; w < 64; w <<= 1) { s += __shfl_xor(s, w); ss += __shfl_xor(ss, w); }

    __shared__ float rs_[4], rss_[4];
    if ((t & 63) == 0) { rs_[t >> 6] = s; rss_[t >> 6] = ss; }
    __syncthreads();
    s  = rs_[0] + rs_[1] + rs_[2] + rs_[3];
    ss = rss_[0] + rss_[1] + rss_[2] + rss_[3];

    const float mean = s * (1.0f / 1024.0f);
    const float var  = ss * (1.0f / 1024.0f) - mean * mean;
    const float rstd = rsqrtf(var + LN_EPS_);

    const float4 g4 = *reinterpret_cast<const float4*>(&gam[t * 4]);
    const float4 b4 = *reinterpret_cast<const float4*>(&bet[t * 4]);
    float4 o;
    o.x = (v.x - mean) * rstd * g4.x + b4.x;
    o.y = (v.y - mean) * rstd * g4.y + b4.y;
    o.z = (v.z - mean) * rstd * g4.z + b4.z;
    o.w = (v.w - mean) * rstd * g4.w + b4.w;
    *reinterpret_cast<float4*>(&out[row * 1024 + t * 4]) = o;
}

// ---------------------------------------------------------------------------
extern "C" void kernel_launch(void* const* d_in, const int* in_sizes, int n_in,
                              void* d_out, int out_size, void* d_ws, size_t ws_size,
                              hipStream_t stream)
{
    const float* q    = (const float*)d_in[0];
    const float* k    = (const float*)d_in[1];
    const float* v    = (const float*)d_in[2];
    const int*   mask = (const int*)d_in[3];
    const float* Wq   = (const float*)d_in[4];
    const float* bq   = (const float*)d_in[5];
    const float* Wk   = (const float*)d_in[6];
    const float* bk   = (const float*)d_in[7];
    const float* Wv   = (const float*)d_in[8];
    const float* bv   = (const float*)d_in[9];
    const float* Wo   = (const float*)d_in[10];
    const float* bo   = (const float*)d_in[11];
    const float* lng  = (const float*)d_in[12];
    const float* lnb  = (const float*)d_in[13];

    float* out      = (float*)d_out;                    // [B,LQ,D]
    float* attn_avg = out + (size_t)B_ * LQ_ * D_;      // [B,LQ,LK]

    const size_t XSZ = (size_t)B_ * LQ_ * D_;           // 8388608 elements
    const size_t WSZ = (size_t)D_ * D_;                 // 1048576

    short* Xq  = (short*)d_ws;
    short* Xk  = Xq + XSZ;
    short* Xv  = Xk + XSZ;
    short* Wtq = Xv + XSZ;
    short* Wtk = Wtq + WSZ;
    short* Wtv = Wtk + WSZ;
    short* Wto = Wtv + WSZ;
    short* qh  = Wto + WSZ;                             // [B,H,LQ,64] bf16 (pre-scaled)
    short* kh  = qh + XSZ;
    short* vT  = kh + XSZ;                              // [B,H,64,LK] bf16
    float* mSt = (float*)(vT + XSZ);                    // [B,H,LQ] base-2 max
    float* sSt = mSt + (size_t)B_ * H_ * LQ_;
    float* maskf = sSt + (size_t)B_ * H_ * LQ_;         // [B,LK]
    float* preln = (float*)d_ws;                        // overlays Xq+Xk (dead after proj)
    short* ctx   = Xv;                                  // overlays Xv (dead after proj)

    cast_x_kernel<<<dim3(4096, 3), 256, 0, stream>>>(q, k, v, mask, Xq, Xk, Xv, maskf);
    cast_wt_kernel<<<dim3(16, 16, 4), 256, 0, stream>>>(Wq, Wk, Wv, Wo, Wtq, Wtk, Wtv, Wto);

    proj_kernel<<<dim3(8, 64, 3), 256, 0, stream>>>(Xq, Xk, Xv, Wtq, Wtk, Wtv,
                                                    bq, bk, bv, qh, kh, vT);

    flash_kernel<<<dim3(32, 16, 4), 256, 0, stream>>>(qh, kh, vT, maskf, ctx, mSt, sSt);

    avg_kernel<<<dim3(32, 32, 4), 256, 0, stream>>>(qh, kh, maskf, mSt, sSt, attn_avg);

    outproj_kernel<<<dim3(8, 64), 256, 0, stream>>>(ctx, Wto, bo, q, preln);

    ln_kernel<<<8192, 256, 0, stream>>>(preln, lng, lnb, out);
}

// Round 4
// 325.523 us; speedup vs baseline: 12.3371x; 1.1933x over previous
//
#include <hip/hip_runtime.h>
#include <hip/hip_bf16.h>
#include <math.h>

#define B_    4
#define LQ_   2048
#define LK_   2048
#define D_    1024
#define H_    16
#define LN_EPS_ 1e-5f
#define NEGINF (-__builtin_inff())
#define QSCALE 0.18033688011112042f   // log2(e)/8 — folded into qh at proj

typedef __attribute__((ext_vector_type(8))) short bf16x8;
typedef __attribute__((ext_vector_type(4))) short bf16x4;
typedef __attribute__((ext_vector_type(4))) float f32x4;

#define MFMA(a, b, c) __builtin_amdgcn_mfma_f32_16x16x32_bf16(a, b, c, 0, 0, 0)

#if __has_builtin(__builtin_amdgcn_exp2f)
#define EXP2(x) __builtin_amdgcn_exp2f(x)
#else
#define EXP2(x) __expf((x) * 0.6931471805599453f)
#endif

__device__ __forceinline__ short f2bf(float f) {
    union { __hip_bfloat16 h; short s; } u;
    u.h = __float2bfloat16(f);
    return u.s;
}

__device__ __forceinline__ void gld16(const short* g, short* l) {
    __builtin_amdgcn_global_load_lds(
        (const __attribute__((address_space(1))) void*)g,
        (__attribute__((address_space(3))) void*)l, 16, 0, 0);
}

// ---------------------------------------------------------------------------
// scan: per batch, compact unmasked key indices.
//   idx[b][j]  = original index of j-th unmasked key (j<cnt), 0 for pad
//   pos[b][l]  = compacted slot of original key l, or -1 if masked
//   maskc[b][j]= 0 for j<cnt, -inf for pad
// ---------------------------------------------------------------------------
__global__ __launch_bounds__(256) void scan_kernel(
    const int* __restrict__ mask, int* __restrict__ idx, int* __restrict__ pos,
    int* __restrict__ cnt, float* __restrict__ maskc)
{
    const int b = blockIdx.x;
    const int t = threadIdx.x;
    const int lane = t & 63, wid = t >> 6;
    __shared__ int wsum[4];
    const int base = b * 2048 + t * 8;

    int fl[8]; int loc = 0;
    #pragma unroll
    for (int j = 0; j < 8; ++j) { fl[j] = (mask[base + j] == 0) ? 1 : 0; loc += fl[j]; }

    int inc = loc;
    #pragma unroll
    for (int d = 1; d < 64; d <<= 1) {
        const int n = __shfl_up(inc, d);
        if (lane >= d) inc += n;
    }
    if (lane == 63) wsum[wid] = inc;
    __syncthreads();
    int wbase = 0;
    for (int i = 0; i < wid; ++i) wbase += wsum[i];
    const int total = wsum[0] + wsum[1] + wsum[2] + wsum[3];

    int e = wbase + inc - loc;   // exclusive prefix for this thread
    #pragma unroll
    for (int j = 0; j < 8; ++j) {
        const int p = t * 8 + j;
        if (fl[j]) { idx[b * 2048 + e] = p; pos[base + j] = e; ++e; }
        else        pos[base + j] = -1;
        maskc[base + j] = (p < total) ? 0.f : NEGINF;
        if (p >= total) idx[base + j] = 0;   // pad-safe gather source
    }
    if (t == 0) cnt[b] = total;
}

// ---------------------------------------------------------------------------
// cast_x: f32 -> bf16 straight copy of q/k/v; also builds additive mask.
// ---------------------------------------------------------------------------
__global__ __launch_bounds__(256) void cast_x_kernel(
    const float* __restrict__ q, const float* __restrict__ k, const float* __restrict__ v,
    const int* __restrict__ mask,
    short* __restrict__ Xq, short* __restrict__ Xk, short* __restrict__ Xv,
    float* __restrict__ maskf)
{
    const int which = blockIdx.y;
    const float* src = which == 0 ? q : (which == 1 ? k : v);
    short* dst       = which == 0 ? Xq : (which == 1 ? Xk : Xv);
    const int t = threadIdx.x;
    const size_t i = ((size_t)blockIdx.x * 256 + t) * 8;
    const float4 a = *reinterpret_cast<const float4*>(src + i);
    const float4 c = *reinterpret_cast<const float4*>(src + i + 4);
    bf16x8 o;
    o[0] = f2bf(a.x); o[1] = f2bf(a.y); o[2] = f2bf(a.z); o[3] = f2bf(a.w);
    o[4] = f2bf(c.x); o[5] = f2bf(c.y); o[6] = f2bf(c.z); o[7] = f2bf(c.w);
    *reinterpret_cast<bf16x8*>(dst + i) = o;
    if (which == 0) {
        const int gid = blockIdx.x * 256 + t;
        if (gid < B_ * LK_) maskf[gid] = (mask[gid] != 0) ? NEGINF : 0.0f;
    }
}

// ---------------------------------------------------------------------------
// cast_wt: W[k][n] f32 -> Wt[n][k] bf16 (transposed), 64x64 LDS tiles.
// ---------------------------------------------------------------------------
__global__ __launch_bounds__(256) void cast_wt_kernel(
    const float* __restrict__ Wq, const float* __restrict__ Wk,
    const float* __restrict__ Wv, const float* __restrict__ Wo,
    short* __restrict__ Wtq, short* __restrict__ Wtk,
    short* __restrict__ Wtv, short* __restrict__ Wto)
{
    const int which = blockIdx.z;
    const float* W = which == 0 ? Wq : (which == 1 ? Wk : (which == 2 ? Wv : Wo));
    short* Wt      = which == 0 ? Wtq : (which == 1 ? Wtk : (which == 2 ? Wtv : Wto));

    __shared__ float T[64][65];
    const int t = threadIdx.x;
    const int k0 = blockIdx.x * 64, n0 = blockIdx.y * 64;
    {
        const int row = t >> 2, cq = (t & 3) * 16;
        #pragma unroll
        for (int i = 0; i < 4; ++i) {
            const float4 v4 = *reinterpret_cast<const float4*>(&W[(size_t)(k0 + row) * 1024 + n0 + cq + i * 4]);
            T[row][cq + i * 4 + 0] = v4.x; T[row][cq + i * 4 + 1] = v4.y;
            T[row][cq + i * 4 + 2] = v4.z; T[row][cq + i * 4 + 3] = v4.w;
        }
    }
    __syncthreads();
    const int nl = t >> 2, kq = (t & 3) * 16;
    bf16x8 o0, o1;
    #pragma unroll
    for (int j = 0; j < 8; ++j) {
        o0[j] = f2bf(T[kq + j][nl]);
        o1[j] = f2bf(T[kq + 8 + j][nl]);
    }
    *reinterpret_cast<bf16x8*>(&Wt[(size_t)(n0 + nl) * 1024 + k0 + kq]) = o0;
    *reinterpret_cast<bf16x8*>(&Wt[(size_t)(n0 + nl) * 1024 + k0 + kq + 8]) = o1;
}

// ---------------------------------------------------------------------------
// proj: C = X(bf16)[M=8192,K=1024] @ Wt^T + bias.  128x128 tile, BK=32.
// which: 0->qh (scaled by log2e/8), 1->kh, 2->vT_c (COMPACTED columns via pos).
// ---------------------------------------------------------------------------
__global__ __launch_bounds__(256) void proj_kernel(
    const short* __restrict__ Xq, const short* __restrict__ Xk, const short* __restrict__ Xv,
    const short* __restrict__ Wtq, const short* __restrict__ Wtk, const short* __restrict__ Wtv,
    const float* __restrict__ bq, const float* __restrict__ bk, const float* __restrict__ bv,
    const int* __restrict__ pos,
    short* __restrict__ qh, short* __restrict__ kh, short* __restrict__ vTc)
{
    const int which = blockIdx.z;
    const short* A  = which == 0 ? Xq : (which == 1 ? Xk : Xv);
    const short* Bt = which == 0 ? Wtq : (which == 1 ? Wtk : Wtv);
    const float* bias = which == 0 ? bq : (which == 1 ? bk : bv);

    __shared__ short Al[4096];   // [128 rows m][32 k], swizzled chunks
    __shared__ short Bl[4096];   // [128 rows n][32 k], swizzled chunks

    const int t = threadIdx.x;
    const int lane = t & 63, w = t >> 6;
    const int wm = w >> 1, wn = w & 1;
    const int g = lane >> 4, r16 = lane & 15;
    const int m0 = blockIdx.y * 128, n0 = blockIdx.x * 128;

    f32x4 acc[4][4] = {};

    for (int k0 = 0; k0 < 1024; k0 += 32) {
        __syncthreads();
        #pragma unroll
        for (int i = 0; i < 2; ++i) {
            const int row = i * 64 + (t >> 2);
            const int cl = (t & 3) ^ ((row >> 1) & 3);
            gld16(A  + (size_t)(m0 + row) * 1024 + k0 + cl * 8, Al + i * 2048 + t * 8);
            gld16(Bt + (size_t)(n0 + row) * 1024 + k0 + cl * 8, Bl + i * 2048 + t * 8);
        }
        __syncthreads();

        bf16x8 af[4], bf[4];
        #pragma unroll
        for (int mf = 0; mf < 4; ++mf) {
            const int row = wm * 64 + mf * 16 + r16;
            af[mf] = *reinterpret_cast<const bf16x8*>(
                (const char*)Al + row * 64 + (((g ^ ((row >> 1) & 3))) << 4));
        }
        #pragma unroll
        for (int nf = 0; nf < 4; ++nf) {
            const int row = wn * 64 + nf * 16 + r16;
            bf[nf] = *reinterpret_cast<const bf16x8*>(
                (const char*)Bl + row * 64 + (((g ^ ((row >> 1) & 3))) << 4));
        }
        #pragma unroll
        for (int mf = 0; mf < 4; ++mf)
            #pragma unroll
            for (int nf = 0; nf < 4; ++nf)
                acc[mf][nf] = MFMA(af[mf], bf[nf], acc[mf][nf]);
    }

    if (which < 2) {
        #pragma unroll
        for (int nf = 0; nf < 4; ++nf) {
            const int n = n0 + wn * 64 + nf * 16 + r16;
            const int h = n >> 6, dh = n & 63;
            const float bn = bias[n];
            #pragma unroll
            for (int mf = 0; mf < 4; ++mf) {
                #pragma unroll
                for (int r = 0; r < 4; ++r) {
                    const int m = m0 + wm * 64 + mf * 16 + 4 * g + r;
                    const int bb = m >> 11, l = m & 2047;
                    float vf = acc[mf][nf][r] + bn;
                    if (which == 0) vf *= QSCALE;       // base-2 logit domain
                    ((which == 0) ? qh : kh)[(((size_t)(bb * H_ + h)) * LQ_ + l) * 64 + dh] = f2bf(vf);
                }
            }
        }
    } else {
        int posr[4][4], bbr[4][4];
        #pragma unroll
        for (int mf = 0; mf < 4; ++mf)
            #pragma unroll
            for (int r = 0; r < 4; ++r) {
                const int m = m0 + wm * 64 + mf * 16 + 4 * g + r;
                const int bb = m >> 11, l = m & 2047;
                bbr[mf][r] = bb;
                posr[mf][r] = pos[bb * 2048 + l];
            }
        #pragma unroll
        for (int nf = 0; nf < 4; ++nf) {
            const int n = n0 + wn * 64 + nf * 16 + r16;
            const int h = n >> 6, dh = n & 63;
            const float bn = bias[n];
            #pragma unroll
            for (int mf = 0; mf < 4; ++mf) {
                #pragma unroll
                for (int r = 0; r < 4; ++r) {
                    const int pc = posr[mf][r];
                    if (pc >= 0)
                        vTc[(((size_t)(bbr[mf][r] * H_ + h)) * 64 + dh) * (size_t)LK_ + pc] =
                            f2bf(acc[mf][nf][r] + bn);
                }
            }
        }
    }
}

// ---------------------------------------------------------------------------
// flash: swapped-QK^T MFMA attention over COMPACTED keys.  Block = (b,h,64q),
// 4 waves x 16 q.  K staged via idx-gather global_load_lds (per-lane global
// addr); V read from compacted vT_c.  Mask C-init only on the last (pad)
// tile.  Base-2 softmax, defer-rescale THR=8.
// ---------------------------------------------------------------------------
__global__ __launch_bounds__(256) void flash_kernel(
    const short* __restrict__ qh, const short* __restrict__ kh, const short* __restrict__ vTc,
    const int* __restrict__ idx, const int* __restrict__ cnt, const float* __restrict__ maskc,
    short* __restrict__ ctx, float* __restrict__ mOut, float* __restrict__ sOut)
{
    const int q0 = blockIdx.x * 64;
    const int h  = blockIdx.y;
    const int b  = blockIdx.z;

    __shared__ short Kl[2][4096];   // [64 k_c][64 d] bf16, 16B-chunk swizzle (^row&7)
    __shared__ short Vl[2][4096];   // [64 dv][64 k_c] bf16, same swizzle

    const int t = threadIdx.x;
    const int lane = t & 63, w = t >> 6;
    const int g = lane >> 4, q16 = lane & 15;

    const short* kbase = kh + (size_t)(b * H_ + h) * LK_ * 64;
    const short* vbase = vTc + (size_t)(b * H_ + h) * 64 * (size_t)LK_;
    const int*   idxb  = idx + b * 2048;
    const int nt = (cnt[b] + 63) >> 6;

    // Q fragments (loop-invariant): pre-scaled by log2e/8 at proj time
    bf16x8 qf0, qf1;
    {
        const short* qrow = qh + ((size_t)(b * H_ + h) * LQ_ + q0 + w * 16 + q16) * 64;
        qf0 = *reinterpret_cast<const bf16x8*>(qrow + 8 * g);
        qf1 = *reinterpret_cast<const bf16x8*>(qrow + 32 + 8 * g);
    }

    // last-tile additive mask (pad columns -inf), in registers
    f32x4 mlast[4] = {};
    if (nt > 0) {
        #pragma unroll
        for (int kb = 0; kb < 4; ++kb)
            mlast[kb] = *reinterpret_cast<const f32x4*>(
                maskc + b * 2048 + (nt - 1) * 64 + kb * 16 + 4 * g);
    }

    const int srw = t >> 3, scl = t & 7;

    f32x4 ot[4] = {};             // O^T frags: dv = 16*fc + 4g + r, q = q16
    float m_run = NEGINF, l_run = 0.f;

    if (nt > 0) {                 // prologue: stage compacted tile 0
        #pragma unroll
        for (int i = 0; i < 2; ++i) {
            const int row = i * 32 + srw;
            const int cl = scl ^ (row & 7);
            const int orig = idxb[row];
            gld16(kbase + (size_t)orig * 64 + cl * 8, Kl[0] + i * 2048 + t * 8);
            gld16(vbase + (size_t)row * LK_ + cl * 8, Vl[0] + i * 2048 + t * 8);
        }
    }
    __syncthreads();

    int cur = 0;
    for (int kt = 0; kt < nt; ++kt) {
        if (kt + 1 < nt) {        // issue next tile's staging
            const int kn = (kt + 1) * 64;
            #pragma unroll
            for (int i = 0; i < 2; ++i) {
                const int row = i * 32 + srw;
                const int cl = scl ^ (row & 7);
                const int orig = idxb[kn + row];
                gld16(kbase + (size_t)orig * 64 + cl * 8, Kl[cur ^ 1] + i * 2048 + t * 8);
                gld16(vbase + (size_t)row * LK_ + kn + cl * 8, Vl[cur ^ 1] + i * 2048 + t * 8);
            }
        }
        const bool lastt = (kt == nt - 1);

        // --- QK^T (swapped): S^T[k][q]; C-init = pad mask on last tile ---
        float lg[4][4];
        const short* klp = Kl[cur];
        __builtin_amdgcn_s_setprio(1);
        #pragma unroll
        for (int kb = 0; kb < 4; ++kb) {
            const int krow = kb * 16 + q16;
            const char* rowp = (const char*)klp + krow * 128;
            const int sw = (krow & 7) << 4;
            const bf16x8 kf0 = *reinterpret_cast<const bf16x8*>(rowp + ((g << 4) ^ sw));
            const bf16x8 kf1 = *reinterpret_cast<const bf16x8*>(rowp + (((4 + g) << 4) ^ sw));
            f32x4 s = lastt ? mlast[kb] : (f32x4){0.f, 0.f, 0.f, 0.f};
            s = MFMA(kf0, qf0, s);
            s = MFMA(kf1, qf1, s);
            #pragma unroll
            for (int r = 0; r < 4; ++r) lg[kb][r] = s[r];
        }
        __builtin_amdgcn_s_setprio(0);

        // --- online softmax (base-2), defer-rescale THR=8 ---
        float tm = NEGINF;
        #pragma unroll
        for (int kb = 0; kb < 4; ++kb)
            #pragma unroll
            for (int r = 0; r < 4; ++r) tm = fmaxf(tm, lg[kb][r]);
        tm = fmaxf(tm, __shfl_xor(tm, 16));
        tm = fmaxf(tm, __shfl_xor(tm, 32));

        const bool skip = __all(tm <= m_run + 8.0f);
        if (!skip) {
            const float m_new = fmaxf(m_run, tm);
            const float alpha = (m_run == NEGINF) ? 0.f : EXP2(m_run - m_new);
            #pragma unroll
            for (int fc = 0; fc < 4; ++fc)
                #pragma unroll
                for (int r = 0; r < 4; ++r) ot[fc][r] *= alpha;
            l_run *= alpha;
            m_run = m_new;
        }
        const float m_use = (m_run == NEGINF) ? 0.f : m_run;

        float p[4][4];
        float ls = 0.f;
        #pragma unroll
        for (int kb = 0; kb < 4; ++kb)
            #pragma unroll
            for (int r = 0; r < 4; ++r) { p[kb][r] = EXP2(lg[kb][r] - m_use); ls += p[kb][r]; }
        ls += __shfl_xor(ls, 16);
        ls += __shfl_xor(ls, 32);
        l_run += ls;

        // pack P^T to bf16 B-frags (k-bijection matches V^T A-frags)
        bf16x8 pb[2];
        #pragma unroll
        for (int r = 0; r < 4; ++r) {
            pb[0][r]     = f2bf(p[0][r]);
            pb[0][4 + r] = f2bf(p[1][r]);
            pb[1][r]     = f2bf(p[2][r]);
            pb[1][4 + r] = f2bf(p[3][r]);
        }

        // --- PV: O^T[dv][q] += mfma(V^T, P^T) ---
        const short* vlp = Vl[cur];
        __builtin_amdgcn_s_setprio(1);
        #pragma unroll
        for (int fc = 0; fc < 4; ++fc) {
            const int dvrow = fc * 16 + q16;
            const char* rowp = (const char*)vlp + dvrow * 128;
            const int sw = (dvrow & 7) << 4;
            #pragma unroll
            for (int tt = 0; tt < 2; ++tt) {
                const bf16x4 va = *reinterpret_cast<const bf16x4*>(rowp + ((64 * tt + 8 * g) ^ sw));
                const bf16x4 vb = *reinterpret_cast<const bf16x4*>(rowp + ((64 * tt + 32 + 8 * g) ^ sw));
                bf16x8 af;
                af[0] = va[0]; af[1] = va[1]; af[2] = va[2]; af[3] = va[3];
                af[4] = vb[0]; af[5] = vb[1]; af[6] = vb[2]; af[7] = vb[3];
                ot[fc] = MFMA(af, pb[tt], ot[fc]);
            }
        }
        __builtin_amdgcn_s_setprio(0);

        __syncthreads();   // drains next-tile gld16s; next iter reads cur^1
        cur ^= 1;
    }

    const float rs = (l_run > 0.f) ? 1.0f / l_run : 0.f;
    short* crow = ctx + ((size_t)b * LQ_ + q0 + w * 16 + q16) * (size_t)(H_ * 64) + h * 64;
    #pragma unroll
    for (int fc = 0; fc < 4; ++fc) {
        bf16x4 o4;
        #pragma unroll
        for (int r = 0; r < 4; ++r) o4[r] = f2bf(ot[fc][r] * rs);
        *reinterpret_cast<bf16x4*>(crow + fc * 16 + 4 * g) = o4;
    }
    if (lane < 16) {
        const size_t idxo = (size_t)(b * H_ + h) * LQ_ + q0 + w * 16 + lane;
        mOut[idxo] = m_run;
        sOut[idxo] = l_run;
    }
}

// ---------------------------------------------------------------------------
// avg: attn_avg[b][q][k] = (1/H) sum_h exp2(l2_h - m2_h)/s_h.  Same fragments
// and MFMA order as flash -> bit-identical logits.  Head-loop double-buffer.
// ---------------------------------------------------------------------------
__global__ __launch_bounds__(256) void avg_kernel(
    const short* __restrict__ qh, const short* __restrict__ kh,
    const float* __restrict__ maskf,
    const float* __restrict__ mS, const float* __restrict__ sS,
    float* __restrict__ attn_avg)
{
    const int k0 = blockIdx.x * 64;
    const int q0 = blockIdx.y * 64;
    const int b  = blockIdx.z;

    __shared__ short Kl[2][4096];

    const int t = threadIdx.x;
    const int lane = t & 63, w = t >> 6;
    const int g = lane >> 4, q16 = lane & 15;

    f32x4 mk[4];
    #pragma unroll
    for (int kb = 0; kb < 4; ++kb)
        mk[kb] = *reinterpret_cast<const f32x4*>(maskf + b * LK_ + k0 + kb * 16 + 4 * g);

    const int srw = t >> 3, scl = t & 7;
    const size_t khbase = (size_t)b * H_ * (size_t)LK_ * 64;

    const short* qbase = qh + ((size_t)b * H_ * LQ_ + q0 + w * 16 + q16) * 64;  // h-stride LQ_*64
    const size_t stbase = (size_t)b * H_ * LQ_ + q0 + w * 16 + q16;             // h-stride LQ_

    {   // prologue: stage head 0
        #pragma unroll
        for (int i = 0; i < 2; ++i) {
            const int row = i * 32 + srw;
            const int cl = scl ^ (row & 7);
            gld16(kh + khbase + (size_t)(k0 + row) * 64 + cl * 8, Kl[0] + i * 2048 + t * 8);
        }
    }
    bf16x8 qf0 = *reinterpret_cast<const bf16x8*>(qbase + 8 * g);
    bf16x8 qf1 = *reinterpret_cast<const bf16x8*>(qbase + 32 + 8 * g);
    float mrow = mS[stbase], srv = sS[stbase];
    __syncthreads();

    f32x4 acc[4] = {};
    int cur = 0;
    for (int hh = 0; hh < H_; ++hh) {
        bf16x8 qn0, qn1; float mn = 0.f, sn = 0.f;
        if (hh + 1 < H_) {
            #pragma unroll
            for (int i = 0; i < 2; ++i) {
                const int row = i * 32 + srw;
                const int cl = scl ^ (row & 7);
                gld16(kh + khbase + (size_t)(hh + 1) * LK_ * 64 + (size_t)(k0 + row) * 64 + cl * 8,
                      Kl[cur ^ 1] + i * 2048 + t * 8);
            }
            const short* qb2 = qbase + (size_t)(hh + 1) * LQ_ * 64;
            qn0 = *reinterpret_cast<const bf16x8*>(qb2 + 8 * g);
            qn1 = *reinterpret_cast<const bf16x8*>(qb2 + 32 + 8 * g);
            mn = mS[stbase + (size_t)(hh + 1) * LQ_];
            sn = sS[stbase + (size_t)(hh + 1) * LQ_];
        }

        const float valid = (mrow == NEGINF || srv <= 0.f) ? 0.f : 1.0f / srv;
        const float m_use = (mrow == NEGINF) ? 0.f : mrow;

        const short* klp = Kl[cur];
        __builtin_amdgcn_s_setprio(1);
        #pragma unroll
        for (int kb = 0; kb < 4; ++kb) {
            const int krow = kb * 16 + q16;
            const char* rowp = (const char*)klp + krow * 128;
            const int sw = (krow & 7) << 4;
            const bf16x8 kf0 = *reinterpret_cast<const bf16x8*>(rowp + ((g << 4) ^ sw));
            const bf16x8 kf1 = *reinterpret_cast<const bf16x8*>(rowp + (((4 + g) << 4) ^ sw));
            f32x4 s = mk[kb];
            s = MFMA(kf0, qf0, s);
            s = MFMA(kf1, qf1, s);
            #pragma unroll
            for (int r = 0; r < 4; ++r)
                acc[kb][r] += EXP2(s[r] - m_use) * valid;
        }
        __builtin_amdgcn_s_setprio(0);

        __syncthreads();
        if (hh + 1 < H_) { qf0 = qn0; qf1 = qn1; mrow = mn; srv = sn; }
        cur ^= 1;
    }

    const float sc = 1.0f / (float)H_;
    float* orow = attn_avg + ((size_t)b * LQ_ + q0 + w * 16 + q16) * (size_t)LK_ + k0;
    #pragma unroll
    for (int kb = 0; kb < 4; ++kb) {
        f32x4 o = acc[kb];
        o[0] *= sc; o[1] *= sc; o[2] *= sc; o[3] *= sc;
        *reinterpret_cast<f32x4*>(orow + kb * 16 + 4 * g) = o;
    }
}

// ---------------------------------------------------------------------------
// outproj: preln = ctx(bf16) @ WoT^T + bo + resid.
// ---------------------------------------------------------------------------
__global__ __launch_bounds__(256) void outproj_kernel(
    const short* __restrict__ ctxIn, const short* __restrict__ Wto,
    const float* __restrict__ bo, const float* __restrict__ resid,
    float* __restrict__ preln)
{
    __shared__ short Al[4096];
    __shared__ short Bl[4096];

    const int t = threadIdx.x;
    const int lane = t & 63, w = t >> 6;
    const int wm = w >> 1, wn = w & 1;
    const int g = lane >> 4, r16 = lane & 15;
    const int m0 = blockIdx.y * 128, n0 = blockIdx.x * 128;

    f32x4 acc[4][4] = {};

    for (int k0 = 0; k0 < 1024; k0 += 32) {
        __syncthreads();
        #pragma unroll
        for (int i = 0; i < 2; ++i) {
            const int row = i * 64 + (t >> 2);
            const int cl = (t & 3) ^ ((row >> 1) & 3);
            gld16(ctxIn + (size_t)(m0 + row) * 1024 + k0 + cl * 8, Al + i * 2048 + t * 8);
            gld16(Wto   + (size_t)(n0 + row) * 1024 + k0 + cl * 8, Bl + i * 2048 + t * 8);
        }
        __syncthreads();

        bf16x8 af[4], bf[4];
        #pragma unroll
        for (int mf = 0; mf < 4; ++mf) {
            const int row = wm * 64 + mf * 16 + r16;
            af[mf] = *reinterpret_cast<const bf16x8*>(
                (const char*)Al + row * 64 + (((g ^ ((row >> 1) & 3))) << 4));
        }
        #pragma unroll
        for (int nf = 0; nf < 4; ++nf) {
            const int row = wn * 64 + nf * 16 + r16;
            bf[nf] = *reinterpret_cast<const bf16x8*>(
                (const char*)Bl + row * 64 + (((g ^ ((row >> 1) & 3))) << 4));
        }
        #pragma unroll
        for (int mf = 0; mf < 4; ++mf)
            #pragma unroll
            for (int nf = 0; nf < 4; ++nf)
                acc[mf][nf] = MFMA(af[mf], bf[nf], acc[mf][nf]);
    }

    #pragma unroll
    for (int nf = 0; nf < 4; ++nf) {
        const int n = n0 + wn * 64 + nf * 16 + r16;
        const float bn = bo[n];
        #pragma unroll
        for (int mf = 0; mf < 4; ++mf) {
            #pragma unroll
            for (int r = 0; r < 4; ++r) {
                const size_t m = m0 + wm * 64 + mf * 16 + 4 * g + r;
                preln[m * 1024 + n] = acc[mf][nf][r] + bn + resid[m * 1024 + n];
            }
        }
    }
}

// ---------------------------------------------------------------------------
// ln: LayerNorm over D=1024, one block per row.
// ---------------------------------------------------------------------------
__global__ __launch_bounds__(256) void ln_kernel(
    const float* __restrict__ xin, const float* __restrict__ gam,
    const float* __restrict__ bet, float* __restrict__ out)
{
    const size_t row = blockIdx.x;
    const int t = threadIdx.x;
    const float4 v = *reinterpret_cast<const float4*>(&xin[row * 1024 + t * 4]);

    float s  = v.x + v.y + v.z + v.w;
    float ss = v.x * v.x + v.y * v.y + v.z * v.z + v.w * v.w;
    #pragma unroll
    for (int w = 1; w < 64; w <<= 1) { s += __shfl_xor(s, w); ss += __shfl_xor(ss, w); }

    __shared__ float rs_[4], rss_[4];
    if ((t & 63) == 0) { rs_[t >> 6] = s; rss_[t >> 6] = ss; }
    __syncthreads();
    s  = rs_[0] + rs_[1] + rs_[2] + rs_[3];
    ss = rss_[0] + rss_[1] + rss_[2] + rss_[3];

    const float mean = s * (1.0f / 1024.0f);
    const float var  = ss * (1.0f / 1024.0f) - mean * mean;
    const float rstd = rsqrtf(var + LN_EPS_);

    const float4 g4 = *reinterpret_cast<const float4*>(&gam[t * 4]);
    const float4 b4 = *reinterpret_cast<const float4*>(&bet[t * 4]);
    float4 o;
    o.x = (v.x - mean) * rstd * g4.x + b4.x;
    o.y = (v.y - mean) * rstd * g4.y + b4.y;
    o.z = (v.z - mean) * rstd * g4.z + b4.z;
    o.w = (v.w - mean) * rstd * g4.w + b4.w;
    *reinterpret_cast<float4*>(&out[row * 1024 + t * 4]) = o;
}

// ---------------------------------------------------------------------------
extern "C" void kernel_launch(void* const* d_in, const int* in_sizes, int n_in,
                              void* d_out, int out_size, void* d_ws, size_t ws_size,
                              hipStream_t stream)
{
    const float* q    = (const float*)d_in[0];
    const float* k    = (const float*)d_in[1];
    const float* v    = (const float*)d_in[2];
    const int*   mask = (const int*)d_in[3];
    const float* Wq   = (const float*)d_in[4];
    const float* bq   = (const float*)d_in[5];
    const float* Wk   = (const float*)d_in[6];
    const float* bk   = (const float*)d_in[7];
    const float* Wv   = (const float*)d_in[8];
    const float* bv   = (const float*)d_in[9];
    const float* Wo   = (const float*)d_in[10];
    const float* bo   = (const float*)d_in[11];
    const float* lng  = (const float*)d_in[12];
    const float* lnb  = (const float*)d_in[13];

    float* out      = (float*)d_out;                    // [B,LQ,D]
    float* attn_avg = out + (size_t)B_ * LQ_ * D_;      // [B,LQ,LK]

    const size_t XSZ = (size_t)B_ * LQ_ * D_;           // 8388608 elements
    const size_t WSZ = (size_t)D_ * D_;                 // 1048576

    short* Xq  = (short*)d_ws;
    short* Xk  = Xq + XSZ;
    short* Xv  = Xk + XSZ;
    short* Wtq = Xv + XSZ;
    short* Wtk = Wtq + WSZ;
    short* Wtv = Wtk + WSZ;
    short* Wto = Wtv + WSZ;
    short* qh  = Wto + WSZ;                             // [B,H,LQ,64] bf16 (pre-scaled)
    short* kh  = qh + XSZ;
    short* vTc = kh + XSZ;                              // [B,H,64,LK] bf16, COMPACTED cols
    float* mSt = (float*)(vTc + XSZ);                   // [B,H,LQ] base-2 max
    float* sSt = mSt + (size_t)B_ * H_ * LQ_;
    float* maskf = sSt + (size_t)B_ * H_ * LQ_;         // [B,LK] additive (full)
    float* maskc = maskf + (size_t)B_ * LK_;            // [B,LK] additive (compacted+pad)
    int*   idx   = (int*)(maskc + (size_t)B_ * LK_);    // [B,LK] compacted -> orig
    int*   pos   = idx + (size_t)B_ * LK_;              // [B,LK] orig -> compacted / -1
    int*   cnt   = pos + (size_t)B_ * LK_;              // [B]
    float* preln = (float*)qh;  // overlays qh+kh (dead after avg); no ctx overlap
    short* ctx   = Xv;          // overlays Xv (dead after proj)

    scan_kernel<<<dim3(B_), 256, 0, stream>>>(mask, idx, pos, cnt, maskc);
    cast_x_kernel<<<dim3(4096, 3), 256, 0, stream>>>(q, k, v, mask, Xq, Xk, Xv, maskf);
    cast_wt_kernel<<<dim3(16, 16, 4), 256, 0, stream>>>(Wq, Wk, Wv, Wo, Wtq, Wtk, Wtv, Wto);

    proj_kernel<<<dim3(8, 64, 3), 256, 0, stream>>>(Xq, Xk, Xv, Wtq, Wtk, Wtv,
                                                    bq, bk, bv, pos, qh, kh, vTc);

    flash_kernel<<<dim3(32, 16, 4), 256, 0, stream>>>(qh, kh, vTc, idx, cnt, maskc,
                                                      ctx, mSt, sSt);

    avg_kernel<<<dim3(32, 32, 4), 256, 0, stream>>>(qh, kh, maskf, mSt, sSt, attn_avg);

    outproj_kernel<<<dim3(8, 64), 256, 0, stream>>>(ctx, Wto, bo, q, preln);

    ln_kernel<<<8192, 256, 0, stream>>>(preln, lng, lnb, out);
}